// Round 21
// baseline (232.538 us; speedup 1.0000x reference)
//
#include <hip/hip_runtime.h>
#include <math.h>

#define LL   4096
#define HH   8
#define DK_  64
#define DV_  64
#define KD_  512
#define NEXP 4

typedef __attribute__((ext_vector_type(8))) short  s16x8;
typedef __attribute__((ext_vector_type(4))) float  f32x4;

__device__ __forceinline__ unsigned short f2bf(float f) {   // RNE f32->bf16
    unsigned u = __float_as_uint(f);
    u += 0x7FFFu + ((u >> 16) & 1u);
    return (unsigned short)(u >> 16);
}

__device__ __forceinline__ void split2(float v, unsigned short& h, unsigned short& l) {
    h = f2bf(v);
    float hf = __uint_as_float((unsigned)h << 16);
    l = f2bf(v - hf);
}

__device__ __forceinline__ float logsig(float x) {
    return fminf(x, 0.f) - log1pf(expf(-fabsf(x)));
}

// ---------------------------------------------------------------------------
// f32 [M][K] -> split-bf16 A layout [M][3K] = [hi | lo | hi]. K = 2^kshift.
// ---------------------------------------------------------------------------
__global__ void cvt_splitA(const float* __restrict__ in, unsigned short* __restrict__ out,
                           int n, int kshift)
{
    int i = blockIdx.x * 256 + threadIdx.x;
    if (i >= n) return;
    unsigned short h, l;
    split2(in[i], h, l);
    int K = 1 << kshift;
    int m = i >> kshift, k = i & (K - 1);
    size_t ro = (size_t)m * 3 * K;
    out[ro + k]         = h;
    out[ro + K + k]     = l;
    out[ro + 2 * K + k] = h;
}

// ---------------------------------------------------------------------------
// ALL weight conversions in one launch. z selects the weight.
// f32 [K][N] -> split-bf16 B layout [N][ld] = [hi|hi|lo] (+zero pad for K=16).
// ---------------------------------------------------------------------------
__global__ void cvt_weights_all(
    const float* __restrict__ Wq,  const float* __restrict__ Wk,  const float* __restrict__ Wv,
    const float* __restrict__ Wqa, const float* __restrict__ Wka, const float* __restrict__ Wga,
    const float* __restrict__ Wg1a,const float* __restrict__ Wg2a,const float* __restrict__ We,
    const float* __restrict__ Wo,  const float* __restrict__ Wqb, const float* __restrict__ Wkb,
    const float* __restrict__ Wgb, const float* __restrict__ Wg1b,const float* __restrict__ Wg2b,
    unsigned short* __restrict__ WallT2, unsigned short* __restrict__ WoT2,
    unsigned short* __restrict__ WqbT2,  unsigned short* __restrict__ WkbT2,
    unsigned short* __restrict__ WgbT2,  unsigned short* __restrict__ Wg1bT2,
    unsigned short* __restrict__ Wg2bT2)
{
    int z = blockIdx.z;
    const float* W; unsigned short* WT; int K, N, ldr, pad = 0;
    switch (z) {
        case 0:  W = Wq;   WT = WallT2;                       K = 1024; N = 512;  ldr = 3072; break;
        case 1:  W = Wk;   WT = WallT2 + (size_t)512 * 3072;  K = 1024; N = 512;  ldr = 3072; break;
        case 2:  W = Wv;   WT = WallT2 + (size_t)1024 * 3072; K = 1024; N = 512;  ldr = 3072; break;
        case 3:  W = Wqa;  WT = WallT2 + (size_t)1536 * 3072; K = 1024; N = 64;   ldr = 3072; break;
        case 4:  W = Wka;  WT = WallT2 + (size_t)1600 * 3072; K = 1024; N = 64;   ldr = 3072; break;
        case 5:  W = Wga;  WT = WallT2 + (size_t)1664 * 3072; K = 1024; N = 64;   ldr = 3072; break;
        case 6:  W = Wg1a; WT = WallT2 + (size_t)1728 * 3072; K = 1024; N = 16;   ldr = 3072; break;
        case 7:  W = Wg2a; WT = WallT2 + (size_t)1744 * 3072; K = 1024; N = 16;   ldr = 3072; break;
        case 8:  W = We;   WT = WallT2 + (size_t)1760 * 3072; K = 1024; N = 4;    ldr = 3072; break;
        case 9:  W = Wo;   WT = WoT2;   K = 512; N = 1024; ldr = 1536; break;
        case 10: W = Wqb;  WT = WqbT2;  K = 64;  N = 512;  ldr = 192;  break;
        case 11: W = Wkb;  WT = WkbT2;  K = 64;  N = 512;  ldr = 192;  break;
        case 12: W = Wgb;  WT = WgbT2;  K = 64;  N = 512;  ldr = 192;  break;
        case 13: W = Wg1b; WT = Wg1bT2; K = 16;  N = 512;  ldr = 64; pad = 1; break;
        default: W = Wg2b; WT = Wg2bT2; K = 16;  N = 512;  ldr = 64; pad = 1; break;
    }
    int bx = blockIdx.x * 32, by = blockIdx.y * 32;
    if (bx >= N || by >= K) return;

    __shared__ float t[32][33];
    int x = threadIdx.x, y = threadIdx.y;
    #pragma unroll
    for (int i = 0; i < 4; ++i) {
        int kk = by + y + 8 * i;
        t[y + 8 * i][x] = (bx + x < N && kk < K) ? W[(size_t)kk * N + bx + x] : 0.f;
    }
    __syncthreads();
    #pragma unroll
    for (int i = 0; i < 4; ++i) {
        int n = bx + y + 8 * i;
        int kidx = by + x;
        if (n < N && kidx < K) {
            unsigned short h, l;
            split2(t[x][y + 8 * i], h, l);
            size_t ro = (size_t)n * ldr + kidx;
            WT[ro]         = h;
            WT[ro + K]     = h;
            WT[ro + 2 * K] = l;
        }
        if (pad && n < N && x < 16)
            WT[(size_t)n * ldr + 3 * K + x] = 0;
    }
}

// ---------------------------------------------------------------------------
// Mega GEMM: [q1|k1|v|tcat] = x @ [Wq|Wk|Wv|Wcat]. 64x128 tile (896 blocks =
// 3.5/CU — grid-starvation fix per m102 shape curve), XCD swizzle, 24KB LDS.
// q1 scaled by 0.125 in epilogue.
// ---------------------------------------------------------------------------
__global__ __launch_bounds__(256) void gemm_qkvcat(
    const unsigned short* __restrict__ A, const unsigned short* __restrict__ B,
    float* __restrict__ Cq, float* __restrict__ Ck, float* __restrict__ Cv,
    float* __restrict__ Ct, int M, int K)
{
    __shared__ __align__(16) unsigned short sm[64 * 64 + 128 * 64];
    unsigned short* As = sm;             // 64 rows x 128B
    unsigned short* Bs = sm + 64 * 64;   // 128 rows x 128B

    int bxi = blockIdx.x, byi = blockIdx.y;
    {
        int gx = gridDim.x, nwg = gx * gridDim.y;
        int b = byi * gx + bxi;
        int s = (b & 7) * (nwg >> 3) + (b >> 3);
        bxi = s % gx; byi = s / gx;
    }

    int tid  = threadIdx.x;
    int lane = tid & 63;
    int w    = tid >> 6;
    int m0 = byi * 64, n0 = bxi * 128;
    int wc = w & 1, wr = w >> 1;         // wr: 32-row half of 64; wc: 64-col half of 128

    f32x4 acc[2][4];
    #pragma unroll
    for (int i = 0; i < 2; ++i)
        #pragma unroll
        for (int j = 0; j < 4; ++j)
            acc[i][j] = (f32x4){0.f, 0.f, 0.f, 0.f};

    const int srow = (lane >> 3);
    const int scb  = ((lane & 7) * 16) ^ (srow << 4);

    for (int kt = 0; kt < K; kt += 64) {
        __syncthreads();
        #pragma unroll
        for (int q = 0; q < 2; ++q) {    // A: 64 rows, 16/wave
            int r = w * 16 + q * 8 + srow;
            const char* ga = (const char*)A + ((size_t)(m0 + r) * K + kt) * 2 + scb;
            __builtin_amdgcn_global_load_lds(
                (const __attribute__((address_space(1))) void*)ga,
                (__attribute__((address_space(3))) void*)((char*)As + (w * 16 + q * 8) * 128),
                16, 0, 0);
        }
        #pragma unroll
        for (int q = 0; q < 4; ++q) {    // B: 128 rows, 32/wave
            int r = w * 32 + q * 8 + srow;
            const char* gb = (const char*)B + ((size_t)(n0 + r) * K + kt) * 2 + scb;
            __builtin_amdgcn_global_load_lds(
                (const __attribute__((address_space(1))) void*)gb,
                (__attribute__((address_space(3))) void*)((char*)Bs + (w * 32 + q * 8) * 128),
                16, 0, 0);
        }
        __syncthreads();

        #pragma unroll
        for (int kk = 0; kk < 2; ++kk) {
            int kb = kk * 64 + (lane >> 4) * 16;
            s16x8 af[2], bfr[4];
            #pragma unroll
            for (int mi = 0; mi < 2; ++mi) {
                int r = wr * 32 + mi * 16 + (lane & 15);
                af[mi] = *(const s16x8*)((const char*)As + r * 128 + (kb ^ ((r & 7) << 4)));
            }
            #pragma unroll
            for (int ni = 0; ni < 4; ++ni) {
                int r = wc * 64 + ni * 16 + (lane & 15);
                bfr[ni] = *(const s16x8*)((const char*)Bs + r * 128 + (kb ^ ((r & 7) << 4)));
            }
            #pragma unroll
            for (int mi = 0; mi < 2; ++mi)
                #pragma unroll
                for (int ni = 0; ni < 4; ++ni)
                    acc[mi][ni] = __builtin_amdgcn_mfma_f32_16x16x32_bf16(
                        af[mi], bfr[ni], acc[mi][ni], 0, 0, 0);
        }
    }

    int base = n0 >> 9;
    float* C;
    int ldc, cb;
    float scale = 1.f;
    if (base == 0)      { C = Cq; ldc = 512; cb = 0; scale = 0.125f; }
    else if (base == 1) { C = Ck; ldc = 512; cb = 512; }
    else if (base == 2) { C = Cv; ldc = 512; cb = 1024; }
    else                { C = Ct; ldc = 256; cb = 1536; }

    #pragma unroll
    for (int mi = 0; mi < 2; ++mi)
        #pragma unroll
        for (int ni = 0; ni < 4; ++ni) {
            int col = n0 + wc * 64 + ni * 16 + (lane & 15) - cb;
            int rb  = m0 + wr * 32 + mi * 16 + (lane >> 4) * 4;
            #pragma unroll
            for (int j = 0; j < 4; ++j)
                C[(size_t)(rb + j) * ldc + col] = acc[mi][ni][j] * scale;
        }
}

// ---------------------------------------------------------------------------
// Split-bf16 MFMA GEMM (Wo). 64x128 tile (512 blocks = 2/CU), XCD swizzle.
// ---------------------------------------------------------------------------
__global__ __launch_bounds__(256) void gemm_mfma(
    const unsigned short* __restrict__ A, const unsigned short* __restrict__ B,
    float* __restrict__ C, int M, int N, int K)
{
    __shared__ __align__(16) unsigned short sm[64 * 64 + 128 * 64];
    unsigned short* As = sm;
    unsigned short* Bs = sm + 64 * 64;

    int bxi = blockIdx.x, byi = blockIdx.y;
    {
        int gx = gridDim.x, nwg = gx * gridDim.y;
        if ((nwg & 7) == 0) {
            int b = byi * gx + bxi;
            int s = (b & 7) * (nwg >> 3) + (b >> 3);
            bxi = s % gx; byi = s / gx;
        }
    }

    int tid  = threadIdx.x;
    int lane = tid & 63;
    int w    = tid >> 6;
    int m0 = byi * 64, n0 = bxi * 128;
    int wc = w & 1, wr = w >> 1;

    f32x4 acc[2][4];
    #pragma unroll
    for (int i = 0; i < 2; ++i)
        #pragma unroll
        for (int j = 0; j < 4; ++j)
            acc[i][j] = (f32x4){0.f, 0.f, 0.f, 0.f};

    const int srow = (lane >> 3);
    const int scb  = ((lane & 7) * 16) ^ (srow << 4);

    for (int kt = 0; kt < K; kt += 64) {
        __syncthreads();
        #pragma unroll
        for (int q = 0; q < 2; ++q) {
            int r = w * 16 + q * 8 + srow;
            const char* ga = (const char*)A + ((size_t)(m0 + r) * K + kt) * 2 + scb;
            __builtin_amdgcn_global_load_lds(
                (const __attribute__((address_space(1))) void*)ga,
                (__attribute__((address_space(3))) void*)((char*)As + (w * 16 + q * 8) * 128),
                16, 0, 0);
        }
        #pragma unroll
        for (int q = 0; q < 4; ++q) {
            int r = w * 32 + q * 8 + srow;
            const char* gb = (const char*)B + ((size_t)(n0 + r) * K + kt) * 2 + scb;
            __builtin_amdgcn_global_load_lds(
                (const __attribute__((address_space(1))) void*)gb,
                (__attribute__((address_space(3))) void*)((char*)Bs + (w * 32 + q * 8) * 128),
                16, 0, 0);
        }
        __syncthreads();

        #pragma unroll
        for (int kk = 0; kk < 2; ++kk) {
            int kb = kk * 64 + (lane >> 4) * 16;
            s16x8 af[2], bfr[4];
            #pragma unroll
            for (int mi = 0; mi < 2; ++mi) {
                int r = wr * 32 + mi * 16 + (lane & 15);
                af[mi] = *(const s16x8*)((const char*)As + r * 128 + (kb ^ ((r & 7) << 4)));
            }
            #pragma unroll
            for (int ni = 0; ni < 4; ++ni) {
                int r = wc * 64 + ni * 16 + (lane & 15);
                bfr[ni] = *(const s16x8*)((const char*)Bs + r * 128 + (kb ^ ((r & 7) << 4)));
            }
            #pragma unroll
            for (int mi = 0; mi < 2; ++mi)
                #pragma unroll
                for (int ni = 0; ni < 4; ++ni)
                    acc[mi][ni] = __builtin_amdgcn_mfma_f32_16x16x32_bf16(
                        af[mi], bfr[ni], acc[mi][ni], 0, 0, 0);
        }
    }

    #pragma unroll
    for (int mi = 0; mi < 2; ++mi)
        #pragma unroll
        for (int ni = 0; ni < 4; ++ni) {
            int col = n0 + wc * 64 + ni * 16 + (lane & 15);
            int rb  = m0 + wr * 32 + mi * 16 + (lane >> 4) * 4;
            #pragma unroll
            for (int j = 0; j < 4; ++j)
                C[(size_t)(rb + j) * N + col] = acc[mi][ni][j];
        }
}

// ---------------------------------------------------------------------------
// Split-bf16 MFMA GEMM, 5-way z with per-z K (192,192,192,64,64). N=512.
// 128x128 tile (640 blocks — already parallel enough). Plain epilogue.
// ---------------------------------------------------------------------------
__global__ __launch_bounds__(256) void gemm_mfma5(
    const unsigned short* __restrict__ A0, const unsigned short* __restrict__ A1,
    const unsigned short* __restrict__ A2, const unsigned short* __restrict__ A3,
    const unsigned short* __restrict__ A4,
    const unsigned short* __restrict__ B0, const unsigned short* __restrict__ B1,
    const unsigned short* __restrict__ B2, const unsigned short* __restrict__ B3,
    const unsigned short* __restrict__ B4,
    float* __restrict__ C0, float* __restrict__ C1, float* __restrict__ C2,
    float* __restrict__ C3, float* __restrict__ C4, int M, int N)
{
    int z = blockIdx.z;
    const unsigned short* A = (z == 0) ? A0 : (z == 1) ? A1 : (z == 2) ? A2 : (z == 3) ? A3 : A4;
    const unsigned short* B = (z == 0) ? B0 : (z == 1) ? B1 : (z == 2) ? B2 : (z == 3) ? B3 : B4;
    float*                C = (z == 0) ? C0 : (z == 1) ? C1 : (z == 2) ? C2 : (z == 3) ? C3 : C4;
    int K = (z < 3) ? 192 : 64;

    __shared__ __align__(16) unsigned short sm[2 * 128 * 64];
    unsigned short* As = sm;
    unsigned short* Bs = sm + 128 * 64;

    int bxi = blockIdx.x, byi = blockIdx.y;
    {
        int gx = gridDim.x, nwg = gx * gridDim.y;
        if ((nwg & 7) == 0) {
            int b = byi * gx + bxi;
            int s = (b & 7) * (nwg >> 3) + (b >> 3);
            bxi = s % gx; byi = s / gx;
        }
    }

    int tid  = threadIdx.x;
    int lane = tid & 63;
    int w    = tid >> 6;
    int m0 = byi * 128, n0 = bxi * 128;
    int wr = w >> 1, wc = w & 1;

    f32x4 acc[4][4];
    #pragma unroll
    for (int i = 0; i < 4; ++i)
        #pragma unroll
        for (int j = 0; j < 4; ++j)
            acc[i][j] = (f32x4){0.f, 0.f, 0.f, 0.f};

    const int srow = (lane >> 3);
    const int scb  = ((lane & 7) * 16) ^ (srow << 4);

    for (int kt = 0; kt < K; kt += 64) {
        __syncthreads();
        #pragma unroll
        for (int q = 0; q < 4; ++q) {
            int r = w * 32 + q * 8 + srow;
            const char* ga = (const char*)A + ((size_t)(m0 + r) * K + kt) * 2 + scb;
            const char* gb = (const char*)B + ((size_t)(n0 + r) * K + kt) * 2 + scb;
            __builtin_amdgcn_global_load_lds(
                (const __attribute__((address_space(1))) void*)ga,
                (__attribute__((address_space(3))) void*)((char*)As + (w * 32 + q * 8) * 128),
                16, 0, 0);
            __builtin_amdgcn_global_load_lds(
                (const __attribute__((address_space(1))) void*)gb,
                (__attribute__((address_space(3))) void*)((char*)Bs + (w * 32 + q * 8) * 128),
                16, 0, 0);
        }
        __syncthreads();

        #pragma unroll
        for (int kk = 0; kk < 2; ++kk) {
            int kb = kk * 64 + (lane >> 4) * 16;
            s16x8 af[4], bfr[4];
            #pragma unroll
            for (int mi = 0; mi < 4; ++mi) {
                int r = wr * 64 + mi * 16 + (lane & 15);
                af[mi] = *(const s16x8*)((const char*)As + r * 128 + (kb ^ ((r & 7) << 4)));
            }
            #pragma unroll
            for (int ni = 0; ni < 4; ++ni) {
                int r = wc * 64 + ni * 16 + (lane & 15);
                bfr[ni] = *(const s16x8*)((const char*)Bs + r * 128 + (kb ^ ((r & 7) << 4)));
            }
            #pragma unroll
            for (int mi = 0; mi < 4; ++mi)
                #pragma unroll
                for (int ni = 0; ni < 4; ++ni)
                    acc[mi][ni] = __builtin_amdgcn_mfma_f32_16x16x32_bf16(
                        af[mi], bfr[ni], acc[mi][ni], 0, 0, 0);
        }
    }

    #pragma unroll
    for (int mi = 0; mi < 4; ++mi)
        #pragma unroll
        for (int ni = 0; ni < 4; ++ni) {
            int col = n0 + wc * 64 + ni * 16 + (lane & 15);
            int rb  = m0 + wr * 64 + mi * 16 + (lane >> 4) * 4;
            #pragma unroll
            for (int j = 0; j < 4; ++j)
                C[(size_t)(rb + j) * N + col] = acc[mi][ni][j];
        }
}

// ---------------------------------------------------------------------------
// Unpack tcat [LL][256]: LoRA-a -> split-bf16 [LL][192]; gate-a -> split-bf16
// [LL][64] (48 used + 16 zero pad); router -> elog f32.
// ---------------------------------------------------------------------------
__global__ void unpack_cat(const float* __restrict__ tcat,
                           unsigned short* __restrict__ tqab2,
                           unsigned short* __restrict__ tkab2,
                           unsigned short* __restrict__ tgab2,
                           unsigned short* __restrict__ tg1s2,
                           unsigned short* __restrict__ tg2s2,
                           float* __restrict__ elog)
{
    int m = blockIdx.x;
    int c = threadIdx.x;
    float vx = tcat[(size_t)m * 256 + c];
    if (c < 192) {
        unsigned short h, l;
        split2(vx, h, l);
        unsigned short* dst = (c < 64) ? tqab2 : (c < 128) ? tkab2 : tgab2;
        int cc = c & 63;
        size_t ro = (size_t)m * 192;
        dst[ro + cc]       = h;
        dst[ro + 64 + cc]  = l;
        dst[ro + 128 + cc] = h;
    } else if (c < 224) {
        unsigned short h, l;
        split2(vx, h, l);
        unsigned short* dst = (c < 208) ? tg1s2 : tg2s2;
        int cc = (c - 192) & 15;
        size_t ro = (size_t)m * 64;
        dst[ro + cc]      = h;
        dst[ro + 16 + cc] = l;
        dst[ro + 32 + cc] = h;
        dst[ro + 48 + cc] = 0;
    } else if (c < 228) {
        elog[(size_t)m * 4 + (c - 224)] = vx;
    }
}

// ---------------------------------------------------------------------------
// Elementwise: q2 scale, k2 softmax per head, gk logsig(+bias)/16, router.
// ---------------------------------------------------------------------------
__global__ void elementwise_pre(float* __restrict__ q2,
                                float* __restrict__ k2, float* __restrict__ gk1,
                                float* __restrict__ gk2,
                                const float* __restrict__ bg1, const float* __restrict__ bg2,
                                const float* __restrict__ elog, float* __restrict__ rw)
{
    int l = blockIdx.x;
    int tid = threadIdx.x;
    int w = tid >> 6, lane = tid & 63;
    int idx = l * KD_ + (w << 6) + lane;

    q2[idx] *= 0.125f;

    float kv = k2[idx];
    float m = kv;
    for (int s = 32; s >= 1; s >>= 1) m = fmaxf(m, __shfl_xor(m, s, 64));
    float ev = expf(kv - m);
    float ssum = ev;
    for (int s = 32; s >= 1; s >>= 1) ssum += __shfl_xor(ssum, s, 64);
    k2[idx] = ev / ssum;

    int bi = (w << 6) + lane;
    gk1[idx] = logsig(gk1[idx] + bg1[bi]) * (1.f / 16.f);
    gk2[idx] = logsig(gk2[idx] + bg2[bi]) * (1.f / 16.f);

    if (tid == 0) {
        float xs[4];
        float mm = -1e30f;
        for (int j = 0; j < 4; ++j) { xs[j] = elog[l * 4 + j]; mm = fmaxf(mm, xs[j]); }
        float s4 = 0.f;
        for (int j = 0; j < 4; ++j) { xs[j] = expf(xs[j] - mm); s4 += xs[j]; }
        for (int j = 0; j < 4; ++j) xs[j] /= s4;
        int arg = 0; float best = xs[0];
        for (int j = 1; j < 4; ++j) if (xs[j] > best) { best = xs[j]; arg = j; }
        for (int j = 0; j < 4; ++j) rw[l * 4 + j] = (j == arg) ? xs[j] : 0.f;
    }
}

// ---------------------------------------------------------------------------
// Phase 1: chunk_kv + decay via split-bf16 MFMA. XCD swizzle over (p,h,c).
// ---------------------------------------------------------------------------
__global__ void gla_kv(const float* __restrict__ k1, const float* __restrict__ k2,
                       const float* __restrict__ gk1, const float* __restrict__ gk2,
                       const float* __restrict__ v, const float* __restrict__ rw,
                       float* __restrict__ kv_all, float* __restrict__ decay_all)
{
    int flat = (blockIdx.z * 8 + blockIdx.y) * 5 + blockIdx.x;
    int sfl = (flat & 7) * 320 + (flat >> 3);
    int p = sfl % 5, h = (sfl / 5) & 7, c = sfl / 40;

    const float* kp = (p == 0) ? k1 : k2;
    const float* gp = (p == 0) ? gk1 : gk2;

    __shared__ __align__(16) unsigned short kgT[64][200];  // [d][hi|lo|hi along t]
    __shared__ __align__(16) unsigned short vT[64][200];   // [e][hi|hi|lo along t]
    __shared__ float glast[64];
    __shared__ float wrow[64];
    __shared__ float segsum[4][64];

    int tid = threadIdx.x;
    int lane = tid & 63, w = tid >> 6;
    int d = lane, seg = w;

    float gkv[16], kvv[16], vv_[16];
    #pragma unroll
    for (int i = 0; i < 16; ++i) {
        size_t base = (size_t)(c * 64 + seg * 16 + i) * KD_ + (h << 6) + d;
        gkv[i] = gp[base];
        kvv[i] = kp[base];
        vv_[i] = v[base];
    }
    if (tid < 64) {
        int lg = c * 64 + tid;
        wrow[tid] = (p == 0) ? 1.f : rw[lg * 4 + (p - 1)];
    }
    __syncthreads();

    {
        float s = 0.f;
        #pragma unroll
        for (int i = 0; i < 16; ++i) {
            int t = seg * 16 + i;
            float xg = gkv[i];
            if (p > 0 && !(wrow[t] > 0.f)) xg = 0.f;
            s += xg;
            gkv[i] = s;
        }
        segsum[seg][d] = s;
    }
    __syncthreads();
    {
        float off = 0.f, tot = 0.f;
        #pragma unroll
        for (int ss = 0; ss < 4; ++ss) {
            float x = segsum[ss][d];
            tot += x;
            if (ss < seg) off += x;
        }
        if (seg == 0) glast[d] = tot;
        #pragma unroll
        for (int i = 0; i < 16; ++i) {
            int t = seg * 16 + i;
            float g = off + gkv[i];
            float kgval = kvv[i] * wrow[t] * expf(-g);
            unsigned short hh, ll;
            split2(kgval, hh, ll);
            kgT[d][t] = hh; kgT[d][64 + t] = ll; kgT[d][128 + t] = hh;
            split2(vv_[i], hh, ll);
            vT[d][t] = hh; vT[d][64 + t] = hh; vT[d][128 + t] = ll;
        }
    }
    __syncthreads();

    size_t base = (size_t)((c * 8 + h) * 5 + p) * 4096;
    int ar = 16 * w + (lane & 15);
    int kb = (lane >> 4) * 16;
    float dec_[4];
    #pragma unroll
    for (int j = 0; j < 4; ++j) dec_[j] = expf(glast[16 * w + (lane >> 4) * 4 + j]);

    #pragma unroll
    for (int ni = 0; ni < 4; ++ni) {
        f32x4 acc = (f32x4){0.f, 0.f, 0.f, 0.f};
        int br = 16 * ni + (lane & 15);
        #pragma unroll
        for (int kk = 0; kk < 6; ++kk) {
            s16x8 af = *(const s16x8*)((const char*)&kgT[ar][0] + kk * 64 + kb);
            s16x8 bf = *(const s16x8*)((const char*)&vT[br][0] + kk * 64 + kb);
            acc = __builtin_amdgcn_mfma_f32_16x16x32_bf16(af, bf, acc, 0, 0, 0);
        }
        #pragma unroll
        for (int j = 0; j < 4; ++j) {
            int dd = 16 * w + (lane >> 4) * 4 + j;
            kv_all[base + dd * 64 + 16 * ni + (lane & 15)] = acc[j] * dec_[j];
        }
    }
    if (tid < 64) decay_all[(size_t)((c * 8 + h) * 5 + p) * 64 + tid] = expf(glast[tid]);
}

// ---------------------------------------------------------------------------
// Inter-chunk state scan: elementwise, in place over kv_all (f32).
// ---------------------------------------------------------------------------
__global__ void gla_state_scan(float* __restrict__ kv, const float* __restrict__ decay)
{
    int gid = blockIdx.x * 256 + threadIdx.x;
    int sub = gid >> 6;
    const size_t stride = 8 * 5 * 64 * 64;
    float S = 0.f;
    float kvv = kv[gid];
    for (int c = 0; c < 64; ++c) {
        size_t o = (size_t)c * stride + gid;
        float nxt = (c < 63) ? kv[o + stride] : 0.f;
        float dec = decay[c * 2560 + sub];
        kv[o] = S;
        S = fmaf(dec, S, kvv);
        kvv = nxt;
    }
}

// ---------------------------------------------------------------------------
// Phase 2: per-pass output via bf16 MFMA. XCD swizzle over (p,h,c).
// ---------------------------------------------------------------------------
__global__ void gla_o(const float* __restrict__ q1, const float* __restrict__ q2,
                      const float* __restrict__ k1, const float* __restrict__ k2,
                      const float* __restrict__ gk1, const float* __restrict__ gk2,
                      const float* __restrict__ v, const float* __restrict__ rw,
                      const float* __restrict__ Spre,
                      float* __restrict__ o_dense, float* __restrict__ o_sparse)
{
    int flat = (blockIdx.z * 8 + blockIdx.y) * 5 + blockIdx.x;
    int sfl = (flat & 7) * 320 + (flat >> 3);
    int p = sfl % 5, h = (sfl / 5) & 7, c = sfl / 40;

    const float* qp = (p == 0) ? q1 : q2;
    const float* kp = (p == 0) ? k1 : k2;
    const float* gp = (p == 0) ? gk1 : gk2;

    __shared__ __align__(16) unsigned short qg_bf[64][72];  // [t][d]
    __shared__ __align__(16) unsigned short kg_bf[64][72];  // [s][d]
    __shared__ __align__(16) unsigned short A_bf[64][72];   // [t][s]
    __shared__ __align__(16) unsigned short vT_bf[64][72];  // [e][s]
    __shared__ __align__(16) unsigned short ST_bf[64][72];  // [e][d]
    __shared__ float wrow[64];
    __shared__ float segsum[4][64];

    int tid = threadIdx.x;
    int lane = tid & 63, w = tid >> 6;
    int d = lane, seg = w;

    {
        float gkv[16], qv[16], kvv[16];
        #pragma unroll
        for (int i = 0; i < 16; ++i) {
            size_t base = (size_t)(c * 64 + seg * 16 + i) * KD_ + (h << 6) + d;
            gkv[i] = gp[base];
            qv[i]  = qp[base];
            kvv[i] = kp[base];
        }
        if (tid < 64) {
            int lg = c * 64 + tid;
            wrow[tid] = (p == 0) ? 1.f : rw[lg * 4 + (p - 1)];
        }
        __syncthreads();

        float s = 0.f;
        #pragma unroll
        for (int i = 0; i < 16; ++i) {
            int t = seg * 16 + i;
            float xg = gkv[i];
            if (p > 0 && !(wrow[t] > 0.f)) xg = 0.f;
            s += xg;
            gkv[i] = s;
        }
        segsum[seg][d] = s;
        __syncthreads();

        float off = 0.f;
        for (int ss = 0; ss < seg; ++ss) off += segsum[ss][d];
        #pragma unroll
        for (int i = 0; i < 16; ++i) {
            int t = seg * 16 + i;
            float g = off + gkv[i];
            float wv = wrow[t];
            qg_bf[t][d] = f2bf(qv[i] * wv * expf(g));
            kg_bf[t][d] = f2bf(kvv[i] * wv * expf(-g));
        }
    }

    {
        size_t sbase = (size_t)((c * 8 + h) * 5 + p) * 4096;
        float Sv[16], vv_[16];
        #pragma unroll
        for (int i = 0; i < 16; ++i) Sv[i] = Spre[sbase + tid + (i << 8)];
        #pragma unroll
        for (int i = 0; i < 16; ++i)
            vv_[i] = v[(size_t)(c * 64 + seg * 16 + i) * KD_ + (h << 6) + d];
        #pragma unroll
        for (int i = 0; i < 16; ++i) ST_bf[d][4 * i + seg] = f2bf(Sv[i]);
        #pragma unroll
        for (int i = 0; i < 16; ++i) vT_bf[d][seg * 16 + i] = f2bf(vv_[i]);
    }
    __syncthreads();

    int am = 16 * w + (lane & 15);
    int kb = (lane >> 4) * 16;

    #pragma unroll
    for (int ni = 0; ni < 4; ++ni) {
        f32x4 acc = (f32x4){0.f, 0.f, 0.f, 0.f};
        if (ni <= w) {
            int br = 16 * ni + (lane & 15);
            #pragma unroll
            for (int kk = 0; kk < 2; ++kk) {
                s16x8 af = *(const s16x8*)((const char*)&qg_bf[am][0] + kk * 64 + kb);
                s16x8 bf = *(const s16x8*)((const char*)&kg_bf[br][0] + kk * 64 + kb);
                acc = __builtin_amdgcn_mfma_f32_16x16x32_bf16(af, bf, acc, 0, 0, 0);
            }
        }
        #pragma unroll
        for (int j = 0; j < 4; ++j) {
            int t = 16 * w + (lane >> 4) * 4 + j;
            int s = 16 * ni + (lane & 15);
            A_bf[t][s] = (s <= t) ? f2bf(acc[j]) : (unsigned short)0;
        }
    }
    __syncthreads();

    #pragma unroll
    for (int ni = 0; ni < 4; ++ni) {
        f32x4 acc = (f32x4){0.f, 0.f, 0.f, 0.f};
        int br = 16 * ni + (lane & 15);
        #pragma unroll
        for (int kk = 0; kk < 2; ++kk) {
            s16x8 af = *(const s16x8*)((const char*)&qg_bf[am][0] + kk * 64 + kb);
            s16x8 bf = *(const s16x8*)((const char*)&ST_bf[br][0] + kk * 64 + kb);
            acc = __builtin_amdgcn_mfma_f32_16x16x32_bf16(af, bf, acc, 0, 0, 0);
        }
        #pragma unroll
        for (int kk = 0; kk < 2; ++kk) {
            s16x8 af = *(const s16x8*)((const char*)&A_bf[am][0] + kk * 64 + kb);
            s16x8 bf = *(const s16x8*)((const char*)&vT_bf[br][0] + kk * 64 + kb);
            acc = __builtin_amdgcn_mfma_f32_16x16x32_bf16(af, bf, acc, 0, 0, 0);
        }
        #pragma unroll
        for (int j = 0; j < 4; ++j) {
            int t = 16 * w + (lane >> 4) * 4 + j;
            int e = 16 * ni + (lane & 15);
            size_t idx = (size_t)(c * 64 + t) * KD_ + (h << 6) + e;
            if (p == 0)                 o_dense[idx]  = acc[j];
            else if (wrow[t] > 0.f)     o_sparse[idx] = acc[j];
        }
    }
}

// ---------------------------------------------------------------------------
// Post: sum dense+sparse, RMS-norm, * norm_w, * silu(g); emit split-bf16 A.
// ---------------------------------------------------------------------------
__global__ void postnorm(const float* __restrict__ o_dense, const float* __restrict__ o_sparse,
                         const float* __restrict__ gbuf,
                         const float* __restrict__ norm_w, unsigned short* __restrict__ og2)
{
    int l = blockIdx.x;
    int tid = threadIdx.x;
    int w = tid >> 6, lane = tid & 63;
    int bi = (w << 6) + lane;
    int idx = l * KD_ + bi;
    float o = o_dense[idx] + o_sparse[idx];
    float ss = o * o;
    for (int s = 32; s >= 1; s >>= 1) ss += __shfl_xor(ss, s, 64);
    float r = rsqrtf(ss * (1.f / 64.f) + 1e-5f);
    float val = o * r * norm_w[lane];
    float gv = gbuf[idx];
    val *= gv / (1.f + expf(-gv));
    unsigned short h, lo;
    split2(val, h, lo);
    size_t ro = (size_t)l * (3 * KD_) + bi;
    og2[ro]           = h;
    og2[ro + KD_]     = lo;
    og2[ro + 2 * KD_] = h;
}

// ---------------------------------------------------------------------------
extern "C" void kernel_launch(void* const* d_in, const int* in_sizes, int n_in,
                              void* d_out, int out_size, void* d_ws, size_t ws_size,
                              hipStream_t stream)
{
    const float* x    = (const float*)d_in[0];
    const float* Wq   = (const float*)d_in[1];
    const float* Wk   = (const float*)d_in[2];
    const float* Wv   = (const float*)d_in[3];
    const float* Wqa  = (const float*)d_in[4];
    const float* Wqb  = (const float*)d_in[5];
    const float* Wka  = (const float*)d_in[6];
    const float* Wkb  = (const float*)d_in[7];
    const float* Wg1a = (const float*)d_in[8];
    const float* Wg1b = (const float*)d_in[9];
    const float* bg1  = (const float*)d_in[10];
    const float* Wg2a = (const float*)d_in[11];
    const float* Wg2b = (const float*)d_in[12];
    const float* bg2  = (const float*)d_in[13];
    const float* We   = (const float*)d_in[14];
    const float* Wga  = (const float*)d_in[15];
    const float* Wgb  = (const float*)d_in[16];
    const float* normw= (const float*)d_in[17];
    const float* Wo   = (const float*)d_in[18];

    float* ws = (float*)d_ws;
    const size_t LKD = (size_t)LL * KD_;   // 2M floats
    float* q1   = ws;
    float* k1   = q1 + LKD;
    float* v    = k1 + LKD;
    float* q2   = v  + LKD;
    float* k2   = q2 + LKD;
    float* gk1  = k2 + LKD;
    float* gk2  = gk1 + LKD;
    float* o_dense  = gk2 + LKD;
    float* o_sparse = o_dense + LKD;
    float* gbuf = o_sparse + LKD;
    float* elog = gbuf + LKD;                  // 4096*4
    float* rw   = elog + (size_t)LL * 4;
    float* kv_all    = rw + (size_t)LL * 4;                    // 10.49M f32
    float* decay_all = kv_all + (size_t)64 * 8 * 5 * 64 * 64;  // 163840 f32

    unsigned short* bp = (unsigned short*)(decay_all + 163840);
    unsigned short* WallT2 = bp; bp += (size_t)1792 * 3072;    // [Wq|Wk|Wv|Wcat]
    unsigned short* WoT2   = bp; bp += (size_t)1024 * 1536;
    unsigned short* WqbT2  = bp; bp += (size_t)512 * 192;
    unsigned short* WkbT2  = bp; bp += (size_t)512 * 192;
    unsigned short* WgbT2  = bp; bp += (size_t)512 * 192;
    unsigned short* Wg1bT2 = bp; bp += (size_t)512 * 64;
    unsigned short* Wg2bT2 = bp; bp += (size_t)512 * 64;
    unsigned short* tqab2  = bp; bp += (size_t)LL * 192;
    unsigned short* tkab2  = bp; bp += (size_t)LL * 192;
    unsigned short* tgab2  = bp; bp += (size_t)LL * 192;
    unsigned short* tg1s2  = bp; bp += (size_t)LL * 64;
    unsigned short* tg2s2  = bp; bp += (size_t)LL * 64;
    float* tcat = (float*)bp;                                  // 4096*256 f32

    // time-multiplexed aliases of kv_all (disjoint lifetimes):
    unsigned short* xb2 = (unsigned short*)kv_all;   // [4096][3072]; dead before gla_kv
    unsigned short* og2 = (unsigned short*)kv_all;   // [4096][1536]; live after gla_o

    dim3 blk(256);
    dim3 tblk(32, 8);

    // ---- conversions ----
    cvt_splitA<<<dim3((LL * 1024 + 255) / 256), blk, 0, stream>>>(x, xb2, LL * 1024, 10);
    hipMemsetAsync(WallT2 + (size_t)1764 * 3072, 0, (size_t)(1792 - 1764) * 3072 * 2, stream);
    cvt_weights_all<<<dim3(32, 32, 15), tblk, 0, stream>>>(
        Wq, Wk, Wv, Wqa, Wka, Wga, Wg1a, Wg2a, We, Wo, Wqb, Wkb, Wgb, Wg1b, Wg2b,
        WallT2, WoT2, WqbT2, WkbT2, WgbT2, Wg1bT2, Wg2bT2);

    // ---- mega GEMM: QKV + LoRA-a + gate-a + router (64x128 tile, 896 blocks) ----
    gemm_qkvcat<<<dim3(14, 64), blk, 0, stream>>>(xb2, WallT2, q1, k1, v, tcat, LL, 3072);
    unpack_cat<<<dim3(LL), blk, 0, stream>>>(tcat, tqab2, tkab2, tgab2, tg1s2, tg2s2, elog);

    // ---- LoRA-b q2,k2,gbuf + gate-b gk1,gk2 ----
    gemm_mfma5<<<dim3(4, 32, 5), blk, 0, stream>>>(
        tqab2, tkab2, tgab2, tg1s2, tg2s2,
        WqbT2, WkbT2, WgbT2, Wg1bT2, Wg2bT2,
        q2, k2, gbuf, gk1, gk2, LL, KD_);

    elementwise_pre<<<LL, 512, 0, stream>>>(q2, k2, gk1, gk2, bg1, bg2, elog, rw);

    // ---- GLA: kv -> scan -> o ----
    gla_kv<<<dim3(5, 8, 64), blk, 0, stream>>>(k1, k2, gk1, gk2, v, rw, kv_all, decay_all);
    gla_state_scan<<<dim3(640), blk, 0, stream>>>(kv_all, decay_all);
    gla_o<<<dim3(5, 8, 64), blk, 0, stream>>>(q1, q2, k1, k2, gk1, gk2, v, rw,
                                              kv_all, o_dense, o_sparse);

    postnorm<<<LL, 512, 0, stream>>>(o_dense, o_sparse, gbuf, normw, og2);

    // ---- output projection (64x128 tile, 512 blocks) ----
    gemm_mfma<<<dim3(8, 64), blk, 0, stream>>>(og2, WoT2, (float*)d_out, LL, 1024, 1536);
}

// Round 22
// 216.536 us; speedup vs baseline: 1.0739x; 1.0739x over previous
//
#include <hip/hip_runtime.h>
#include <math.h>

#define LL   4096
#define HH   8
#define DK_  64
#define DV_  64
#define KD_  512
#define NEXP 4

typedef __attribute__((ext_vector_type(8))) short  s16x8;
typedef __attribute__((ext_vector_type(4))) float  f32x4;

__device__ __forceinline__ unsigned short f2bf(float f) {   // RNE f32->bf16
    unsigned u = __float_as_uint(f);
    u += 0x7FFFu + ((u >> 16) & 1u);
    return (unsigned short)(u >> 16);
}

__device__ __forceinline__ void split2(float v, unsigned short& h, unsigned short& l) {
    h = f2bf(v);
    float hf = __uint_as_float((unsigned)h << 16);
    l = f2bf(v - hf);
}

__device__ __forceinline__ float logsig(float x) {
    return fminf(x, 0.f) - log1pf(expf(-fabsf(x)));
}

// ---------------------------------------------------------------------------
// f32 [M][K] -> split-bf16 A layout [M][3K] = [hi | lo | hi]. K = 2^kshift.
// ---------------------------------------------------------------------------
__global__ void cvt_splitA(const float* __restrict__ in, unsigned short* __restrict__ out,
                           int n, int kshift)
{
    int i = blockIdx.x * 256 + threadIdx.x;
    if (i >= n) return;
    unsigned short h, l;
    split2(in[i], h, l);
    int K = 1 << kshift;
    int m = i >> kshift, k = i & (K - 1);
    size_t ro = (size_t)m * 3 * K;
    out[ro + k]         = h;
    out[ro + K + k]     = l;
    out[ro + 2 * K + k] = h;
}

// ---------------------------------------------------------------------------
// ALL weight conversions in one launch. z selects the weight.
// f32 [K][N] -> split-bf16 B layout [N][ld] = [hi|hi|lo] (+zero pad for K=16).
// ---------------------------------------------------------------------------
__global__ void cvt_weights_all(
    const float* __restrict__ Wq,  const float* __restrict__ Wk,  const float* __restrict__ Wv,
    const float* __restrict__ Wqa, const float* __restrict__ Wka, const float* __restrict__ Wga,
    const float* __restrict__ Wg1a,const float* __restrict__ Wg2a,const float* __restrict__ We,
    const float* __restrict__ Wo,  const float* __restrict__ Wqb, const float* __restrict__ Wkb,
    const float* __restrict__ Wgb, const float* __restrict__ Wg1b,const float* __restrict__ Wg2b,
    unsigned short* __restrict__ WallT2, unsigned short* __restrict__ WoT2,
    unsigned short* __restrict__ WqbT2,  unsigned short* __restrict__ WkbT2,
    unsigned short* __restrict__ WgbT2,  unsigned short* __restrict__ Wg1bT2,
    unsigned short* __restrict__ Wg2bT2)
{
    int z = blockIdx.z;
    const float* W; unsigned short* WT; int K, N, ldr, pad = 0;
    switch (z) {
        case 0:  W = Wq;   WT = WallT2;                       K = 1024; N = 512;  ldr = 3072; break;
        case 1:  W = Wk;   WT = WallT2 + (size_t)512 * 3072;  K = 1024; N = 512;  ldr = 3072; break;
        case 2:  W = Wv;   WT = WallT2 + (size_t)1024 * 3072; K = 1024; N = 512;  ldr = 3072; break;
        case 3:  W = Wqa;  WT = WallT2 + (size_t)1536 * 3072; K = 1024; N = 64;   ldr = 3072; break;
        case 4:  W = Wka;  WT = WallT2 + (size_t)1600 * 3072; K = 1024; N = 64;   ldr = 3072; break;
        case 5:  W = Wga;  WT = WallT2 + (size_t)1664 * 3072; K = 1024; N = 64;   ldr = 3072; break;
        case 6:  W = Wg1a; WT = WallT2 + (size_t)1728 * 3072; K = 1024; N = 16;   ldr = 3072; break;
        case 7:  W = Wg2a; WT = WallT2 + (size_t)1744 * 3072; K = 1024; N = 16;   ldr = 3072; break;
        case 8:  W = We;   WT = WallT2 + (size_t)1760 * 3072; K = 1024; N = 4;    ldr = 3072; break;
        case 9:  W = Wo;   WT = WoT2;   K = 512; N = 1024; ldr = 1536; break;
        case 10: W = Wqb;  WT = WqbT2;  K = 64;  N = 512;  ldr = 192;  break;
        case 11: W = Wkb;  WT = WkbT2;  K = 64;  N = 512;  ldr = 192;  break;
        case 12: W = Wgb;  WT = WgbT2;  K = 64;  N = 512;  ldr = 192;  break;
        case 13: W = Wg1b; WT = Wg1bT2; K = 16;  N = 512;  ldr = 64; pad = 1; break;
        default: W = Wg2b; WT = Wg2bT2; K = 16;  N = 512;  ldr = 64; pad = 1; break;
    }
    int bx = blockIdx.x * 32, by = blockIdx.y * 32;
    if (bx >= N || by >= K) return;

    __shared__ float t[32][33];
    int x = threadIdx.x, y = threadIdx.y;
    #pragma unroll
    for (int i = 0; i < 4; ++i) {
        int kk = by + y + 8 * i;
        t[y + 8 * i][x] = (bx + x < N && kk < K) ? W[(size_t)kk * N + bx + x] : 0.f;
    }
    __syncthreads();
    #pragma unroll
    for (int i = 0; i < 4; ++i) {
        int n = bx + y + 8 * i;
        int kidx = by + x;
        if (n < N && kidx < K) {
            unsigned short h, l;
            split2(t[x][y + 8 * i], h, l);
            size_t ro = (size_t)n * ldr + kidx;
            WT[ro]         = h;
            WT[ro + K]     = h;
            WT[ro + 2 * K] = l;
        }
        if (pad && n < N && x < 16)
            WT[(size_t)n * ldr + 3 * K + x] = 0;
    }
}

// ---------------------------------------------------------------------------
// Mega GEMM: [q1|k1|v|tcat] = x @ [Wq|Wk|Wv|Wcat]. 128x128 tile, XCD swizzle,
// ISSUE-EARLY PREFETCH dbuf (64KB LDS — free: grid-limited at 1.75 blk/CU).
// q1 scaled by 0.125 in epilogue.
// ---------------------------------------------------------------------------
__global__ __launch_bounds__(256) void gemm_qkvcat(
    const unsigned short* __restrict__ A, const unsigned short* __restrict__ B,
    float* __restrict__ Cq, float* __restrict__ Ck, float* __restrict__ Cv,
    float* __restrict__ Ct, int M, int K)
{
    __shared__ __align__(16) unsigned short sm[4 * 128 * 64];   // 2 bufs x (A+B)

    int bxi = blockIdx.x, byi = blockIdx.y;
    {
        int gx = gridDim.x, nwg = gx * gridDim.y;
        int b = byi * gx + bxi;
        int s = (b & 7) * (nwg >> 3) + (b >> 3);
        bxi = s % gx; byi = s / gx;
    }

    int tid  = threadIdx.x;
    int lane = tid & 63;
    int w    = tid >> 6;
    int m0 = byi * 128, n0 = bxi * 128;
    int wr = w >> 1, wc = w & 1;

    f32x4 acc[4][4];
    #pragma unroll
    for (int i = 0; i < 4; ++i)
        #pragma unroll
        for (int j = 0; j < 4; ++j)
            acc[i][j] = (f32x4){0.f, 0.f, 0.f, 0.f};

    const int srow = (lane >> 3);
    const int scb  = ((lane & 7) * 16) ^ (srow << 4);

    auto stage = [&](int buf, int kt) {
        unsigned short* Asb = sm + buf * (2 * 128 * 64);
        unsigned short* Bsb = Asb + 128 * 64;
        #pragma unroll
        for (int q = 0; q < 4; ++q) {
            int r = w * 32 + q * 8 + srow;
            const char* ga = (const char*)A + ((size_t)(m0 + r) * K + kt) * 2 + scb;
            const char* gb = (const char*)B + ((size_t)(n0 + r) * K + kt) * 2 + scb;
            __builtin_amdgcn_global_load_lds(
                (const __attribute__((address_space(1))) void*)ga,
                (__attribute__((address_space(3))) void*)((char*)Asb + (w * 32 + q * 8) * 128),
                16, 0, 0);
            __builtin_amdgcn_global_load_lds(
                (const __attribute__((address_space(1))) void*)gb,
                (__attribute__((address_space(3))) void*)((char*)Bsb + (w * 32 + q * 8) * 128),
                16, 0, 0);
        }
    };

    stage(0, 0);
    __syncthreads();
    int cur = 0;
    for (int kt = 0; kt < K; kt += 64) {
        if (kt + 64 < K) stage(cur ^ 1, kt + 64);   // issue next-tile loads EARLY
        unsigned short* Asb = sm + cur * (2 * 128 * 64);
        unsigned short* Bsb = Asb + 128 * 64;
        #pragma unroll
        for (int kk = 0; kk < 2; ++kk) {
            int kb = kk * 64 + (lane >> 4) * 16;
            s16x8 af[4], bfr[4];
            #pragma unroll
            for (int mi = 0; mi < 4; ++mi) {
                int r = wr * 64 + mi * 16 + (lane & 15);
                af[mi] = *(const s16x8*)((const char*)Asb + r * 128 + (kb ^ ((r & 7) << 4)));
            }
            #pragma unroll
            for (int ni = 0; ni < 4; ++ni) {
                int r = wc * 64 + ni * 16 + (lane & 15);
                bfr[ni] = *(const s16x8*)((const char*)Bsb + r * 128 + (kb ^ ((r & 7) << 4)));
            }
            #pragma unroll
            for (int mi = 0; mi < 4; ++mi)
                #pragma unroll
                for (int ni = 0; ni < 4; ++ni)
                    acc[mi][ni] = __builtin_amdgcn_mfma_f32_16x16x32_bf16(
                        af[mi], bfr[ni], acc[mi][ni], 0, 0, 0);
        }
        __syncthreads();    // one drain per K-tile (prefetch covered by MFMA phase)
        cur ^= 1;
    }

    int base = n0 >> 9;
    float* C;
    int ldc, cb;
    float scale = 1.f;
    if (base == 0)      { C = Cq; ldc = 512; cb = 0; scale = 0.125f; }
    else if (base == 1) { C = Ck; ldc = 512; cb = 512; }
    else if (base == 2) { C = Cv; ldc = 512; cb = 1024; }
    else                { C = Ct; ldc = 256; cb = 1536; }

    #pragma unroll
    for (int mi = 0; mi < 4; ++mi)
        #pragma unroll
        for (int ni = 0; ni < 4; ++ni) {
            int col = n0 + wc * 64 + ni * 16 + (lane & 15) - cb;
            int rb  = m0 + wr * 64 + mi * 16 + (lane >> 4) * 4;
            #pragma unroll
            for (int j = 0; j < 4; ++j)
                C[(size_t)(rb + j) * ldc + col] = acc[mi][ni][j] * scale;
        }
}

// ---------------------------------------------------------------------------
// Split-bf16 MFMA GEMM (Wo). 64x128 tile (512 blocks = 2/CU), XCD swizzle.
// ---------------------------------------------------------------------------
__global__ __launch_bounds__(256) void gemm_mfma(
    const unsigned short* __restrict__ A, const unsigned short* __restrict__ B,
    float* __restrict__ C, int M, int N, int K)
{
    __shared__ __align__(16) unsigned short sm[64 * 64 + 128 * 64];
    unsigned short* As = sm;
    unsigned short* Bs = sm + 64 * 64;

    int bxi = blockIdx.x, byi = blockIdx.y;
    {
        int gx = gridDim.x, nwg = gx * gridDim.y;
        if ((nwg & 7) == 0) {
            int b = byi * gx + bxi;
            int s = (b & 7) * (nwg >> 3) + (b >> 3);
            bxi = s % gx; byi = s / gx;
        }
    }

    int tid  = threadIdx.x;
    int lane = tid & 63;
    int w    = tid >> 6;
    int m0 = byi * 64, n0 = bxi * 128;
    int wc = w & 1, wr = w >> 1;

    f32x4 acc[2][4];
    #pragma unroll
    for (int i = 0; i < 2; ++i)
        #pragma unroll
        for (int j = 0; j < 4; ++j)
            acc[i][j] = (f32x4){0.f, 0.f, 0.f, 0.f};

    const int srow = (lane >> 3);
    const int scb  = ((lane & 7) * 16) ^ (srow << 4);

    for (int kt = 0; kt < K; kt += 64) {
        __syncthreads();
        #pragma unroll
        for (int q = 0; q < 2; ++q) {
            int r = w * 16 + q * 8 + srow;
            const char* ga = (const char*)A + ((size_t)(m0 + r) * K + kt) * 2 + scb;
            __builtin_amdgcn_global_load_lds(
                (const __attribute__((address_space(1))) void*)ga,
                (__attribute__((address_space(3))) void*)((char*)As + (w * 16 + q * 8) * 128),
                16, 0, 0);
        }
        #pragma unroll
        for (int q = 0; q < 4; ++q) {
            int r = w * 32 + q * 8 + srow;
            const char* gb = (const char*)B + ((size_t)(n0 + r) * K + kt) * 2 + scb;
            __builtin_amdgcn_global_load_lds(
                (const __attribute__((address_space(1))) void*)gb,
                (__attribute__((address_space(3))) void*)((char*)Bs + (w * 32 + q * 8) * 128),
                16, 0, 0);
        }
        __syncthreads();

        #pragma unroll
        for (int kk = 0; kk < 2; ++kk) {
            int kb = kk * 64 + (lane >> 4) * 16;
            s16x8 af[2], bfr[4];
            #pragma unroll
            for (int mi = 0; mi < 2; ++mi) {
                int r = wr * 32 + mi * 16 + (lane & 15);
                af[mi] = *(const s16x8*)((const char*)As + r * 128 + (kb ^ ((r & 7) << 4)));
            }
            #pragma unroll
            for (int ni = 0; ni < 4; ++ni) {
                int r = wc * 64 + ni * 16 + (lane & 15);
                bfr[ni] = *(const s16x8*)((const char*)Bs + r * 128 + (kb ^ ((r & 7) << 4)));
            }
            #pragma unroll
            for (int mi = 0; mi < 2; ++mi)
                #pragma unroll
                for (int ni = 0; ni < 4; ++ni)
                    acc[mi][ni] = __builtin_amdgcn_mfma_f32_16x16x32_bf16(
                        af[mi], bfr[ni], acc[mi][ni], 0, 0, 0);
        }
    }

    #pragma unroll
    for (int mi = 0; mi < 2; ++mi)
        #pragma unroll
        for (int ni = 0; ni < 4; ++ni) {
            int col = n0 + wc * 64 + ni * 16 + (lane & 15);
            int rb  = m0 + wr * 32 + mi * 16 + (lane >> 4) * 4;
            #pragma unroll
            for (int j = 0; j < 4; ++j)
                C[(size_t)(rb + j) * N + col] = acc[mi][ni][j];
        }
}

// ---------------------------------------------------------------------------
// Split-bf16 MFMA GEMM, 5-way z with per-z K (192,192,192,64,64). N=512.
// 128x128 tile, single buffer, plain epilogue.
// ---------------------------------------------------------------------------
__global__ __launch_bounds__(256) void gemm_mfma5(
    const unsigned short* __restrict__ A0, const unsigned short* __restrict__ A1,
    const unsigned short* __restrict__ A2, const unsigned short* __restrict__ A3,
    const unsigned short* __restrict__ A4,
    const unsigned short* __restrict__ B0, const unsigned short* __restrict__ B1,
    const unsigned short* __restrict__ B2, const unsigned short* __restrict__ B3,
    const unsigned short* __restrict__ B4,
    float* __restrict__ C0, float* __restrict__ C1, float* __restrict__ C2,
    float* __restrict__ C3, float* __restrict__ C4, int M, int N)
{
    int z = blockIdx.z;
    const unsigned short* A = (z == 0) ? A0 : (z == 1) ? A1 : (z == 2) ? A2 : (z == 3) ? A3 : A4;
    const unsigned short* B = (z == 0) ? B0 : (z == 1) ? B1 : (z == 2) ? B2 : (z == 3) ? B3 : B4;
    float*                C = (z == 0) ? C0 : (z == 1) ? C1 : (z == 2) ? C2 : (z == 3) ? C3 : C4;
    int K = (z < 3) ? 192 : 64;

    __shared__ __align__(16) unsigned short sm[2 * 128 * 64];
    unsigned short* As = sm;
    unsigned short* Bs = sm + 128 * 64;

    int bxi = blockIdx.x, byi = blockIdx.y;
    {
        int gx = gridDim.x, nwg = gx * gridDim.y;
        if ((nwg & 7) == 0) {
            int b = byi * gx + bxi;
            int s = (b & 7) * (nwg >> 3) + (b >> 3);
            bxi = s % gx; byi = s / gx;
        }
    }

    int tid  = threadIdx.x;
    int lane = tid & 63;
    int w    = tid >> 6;
    int m0 = byi * 128, n0 = bxi * 128;
    int wr = w >> 1, wc = w & 1;

    f32x4 acc[4][4];
    #pragma unroll
    for (int i = 0; i < 4; ++i)
        #pragma unroll
        for (int j = 0; j < 4; ++j)
            acc[i][j] = (f32x4){0.f, 0.f, 0.f, 0.f};

    const int srow = (lane >> 3);
    const int scb  = ((lane & 7) * 16) ^ (srow << 4);

    for (int kt = 0; kt < K; kt += 64) {
        __syncthreads();
        #pragma unroll
        for (int q = 0; q < 4; ++q) {
            int r = w * 32 + q * 8 + srow;
            const char* ga = (const char*)A + ((size_t)(m0 + r) * K + kt) * 2 + scb;
            const char* gb = (const char*)B + ((size_t)(n0 + r) * K + kt) * 2 + scb;
            __builtin_amdgcn_global_load_lds(
                (const __attribute__((address_space(1))) void*)ga,
                (__attribute__((address_space(3))) void*)((char*)As + (w * 32 + q * 8) * 128),
                16, 0, 0);
            __builtin_amdgcn_global_load_lds(
                (const __attribute__((address_space(1))) void*)gb,
                (__attribute__((address_space(3))) void*)((char*)Bs + (w * 32 + q * 8) * 128),
                16, 0, 0);
        }
        __syncthreads();

        #pragma unroll
        for (int kk = 0; kk < 2; ++kk) {
            int kb = kk * 64 + (lane >> 4) * 16;
            s16x8 af[4], bfr[4];
            #pragma unroll
            for (int mi = 0; mi < 4; ++mi) {
                int r = wr * 64 + mi * 16 + (lane & 15);
                af[mi] = *(const s16x8*)((const char*)As + r * 128 + (kb ^ ((r & 7) << 4)));
            }
            #pragma unroll
            for (int ni = 0; ni < 4; ++ni) {
                int r = wc * 64 + ni * 16 + (lane & 15);
                bfr[ni] = *(const s16x8*)((const char*)Bs + r * 128 + (kb ^ ((r & 7) << 4)));
            }
            #pragma unroll
            for (int mi = 0; mi < 4; ++mi)
                #pragma unroll
                for (int ni = 0; ni < 4; ++ni)
                    acc[mi][ni] = __builtin_amdgcn_mfma_f32_16x16x32_bf16(
                        af[mi], bfr[ni], acc[mi][ni], 0, 0, 0);
        }
    }

    #pragma unroll
    for (int mi = 0; mi < 4; ++mi)
        #pragma unroll
        for (int ni = 0; ni < 4; ++ni) {
            int col = n0 + wc * 64 + ni * 16 + (lane & 15);
            int rb  = m0 + wr * 64 + mi * 16 + (lane >> 4) * 4;
            #pragma unroll
            for (int j = 0; j < 4; ++j)
                C[(size_t)(rb + j) * N + col] = acc[mi][ni][j];
        }
}

// ---------------------------------------------------------------------------
// Unpack tcat [LL][256]: LoRA-a -> split-bf16 [LL][192]; gate-a -> split-bf16
// [LL][64] (48 used + 16 zero pad); router -> elog f32.
// ---------------------------------------------------------------------------
__global__ void unpack_cat(const float* __restrict__ tcat,
                           unsigned short* __restrict__ tqab2,
                           unsigned short* __restrict__ tkab2,
                           unsigned short* __restrict__ tgab2,
                           unsigned short* __restrict__ tg1s2,
                           unsigned short* __restrict__ tg2s2,
                           float* __restrict__ elog)
{
    int m = blockIdx.x;
    int c = threadIdx.x;
    float vx = tcat[(size_t)m * 256 + c];
    if (c < 192) {
        unsigned short h, l;
        split2(vx, h, l);
        unsigned short* dst = (c < 64) ? tqab2 : (c < 128) ? tkab2 : tgab2;
        int cc = c & 63;
        size_t ro = (size_t)m * 192;
        dst[ro + cc]       = h;
        dst[ro + 64 + cc]  = l;
        dst[ro + 128 + cc] = h;
    } else if (c < 224) {
        unsigned short h, l;
        split2(vx, h, l);
        unsigned short* dst = (c < 208) ? tg1s2 : tg2s2;
        int cc = (c - 192) & 15;
        size_t ro = (size_t)m * 64;
        dst[ro + cc]      = h;
        dst[ro + 16 + cc] = l;
        dst[ro + 32 + cc] = h;
        dst[ro + 48 + cc] = 0;
    } else if (c < 228) {
        elog[(size_t)m * 4 + (c - 224)] = vx;
    }
}

// ---------------------------------------------------------------------------
// Elementwise: q2 scale, k2 softmax per head, gk logsig(+bias)/16, router.
// ---------------------------------------------------------------------------
__global__ void elementwise_pre(float* __restrict__ q2,
                                float* __restrict__ k2, float* __restrict__ gk1,
                                float* __restrict__ gk2,
                                const float* __restrict__ bg1, const float* __restrict__ bg2,
                                const float* __restrict__ elog, float* __restrict__ rw)
{
    int l = blockIdx.x;
    int tid = threadIdx.x;
    int w = tid >> 6, lane = tid & 63;
    int idx = l * KD_ + (w << 6) + lane;

    q2[idx] *= 0.125f;

    float kv = k2[idx];
    float m = kv;
    for (int s = 32; s >= 1; s >>= 1) m = fmaxf(m, __shfl_xor(m, s, 64));
    float ev = expf(kv - m);
    float ssum = ev;
    for (int s = 32; s >= 1; s >>= 1) ssum += __shfl_xor(ssum, s, 64);
    k2[idx] = ev / ssum;

    int bi = (w << 6) + lane;
    gk1[idx] = logsig(gk1[idx] + bg1[bi]) * (1.f / 16.f);
    gk2[idx] = logsig(gk2[idx] + bg2[bi]) * (1.f / 16.f);

    if (tid == 0) {
        float xs[4];
        float mm = -1e30f;
        for (int j = 0; j < 4; ++j) { xs[j] = elog[l * 4 + j]; mm = fmaxf(mm, xs[j]); }
        float s4 = 0.f;
        for (int j = 0; j < 4; ++j) { xs[j] = expf(xs[j] - mm); s4 += xs[j]; }
        for (int j = 0; j < 4; ++j) xs[j] /= s4;
        int arg = 0; float best = xs[0];
        for (int j = 1; j < 4; ++j) if (xs[j] > best) { best = xs[j]; arg = j; }
        for (int j = 0; j < 4; ++j) rw[l * 4 + j] = (j == arg) ? xs[j] : 0.f;
    }
}

// ---------------------------------------------------------------------------
// Phase 1: chunk_kv + decay via split-bf16 MFMA. XCD swizzle over (p,h,c).
// ---------------------------------------------------------------------------
__global__ void gla_kv(const float* __restrict__ k1, const float* __restrict__ k2,
                       const float* __restrict__ gk1, const float* __restrict__ gk2,
                       const float* __restrict__ v, const float* __restrict__ rw,
                       float* __restrict__ kv_all, float* __restrict__ decay_all)
{
    int flat = (blockIdx.z * 8 + blockIdx.y) * 5 + blockIdx.x;
    int sfl = (flat & 7) * 320 + (flat >> 3);
    int p = sfl % 5, h = (sfl / 5) & 7, c = sfl / 40;

    const float* kp = (p == 0) ? k1 : k2;
    const float* gp = (p == 0) ? gk1 : gk2;

    __shared__ __align__(16) unsigned short kgT[64][200];  // [d][hi|lo|hi along t]
    __shared__ __align__(16) unsigned short vT[64][200];   // [e][hi|hi|lo along t]
    __shared__ float glast[64];
    __shared__ float wrow[64];
    __shared__ float segsum[4][64];

    int tid = threadIdx.x;
    int lane = tid & 63, w = tid >> 6;
    int d = lane, seg = w;

    float gkv[16], kvv[16], vv_[16];
    #pragma unroll
    for (int i = 0; i < 16; ++i) {
        size_t base = (size_t)(c * 64 + seg * 16 + i) * KD_ + (h << 6) + d;
        gkv[i] = gp[base];
        kvv[i] = kp[base];
        vv_[i] = v[base];
    }
    if (tid < 64) {
        int lg = c * 64 + tid;
        wrow[tid] = (p == 0) ? 1.f : rw[lg * 4 + (p - 1)];
    }
    __syncthreads();

    {
        float s = 0.f;
        #pragma unroll
        for (int i = 0; i < 16; ++i) {
            int t = seg * 16 + i;
            float xg = gkv[i];
            if (p > 0 && !(wrow[t] > 0.f)) xg = 0.f;
            s += xg;
            gkv[i] = s;
        }
        segsum[seg][d] = s;
    }
    __syncthreads();
    {
        float off = 0.f, tot = 0.f;
        #pragma unroll
        for (int ss = 0; ss < 4; ++ss) {
            float x = segsum[ss][d];
            tot += x;
            if (ss < seg) off += x;
        }
        if (seg == 0) glast[d] = tot;
        #pragma unroll
        for (int i = 0; i < 16; ++i) {
            int t = seg * 16 + i;
            float g = off + gkv[i];
            float kgval = kvv[i] * wrow[t] * expf(-g);
            unsigned short hh, ll;
            split2(kgval, hh, ll);
            kgT[d][t] = hh; kgT[d][64 + t] = ll; kgT[d][128 + t] = hh;
            split2(vv_[i], hh, ll);
            vT[d][t] = hh; vT[d][64 + t] = hh; vT[d][128 + t] = ll;
        }
    }
    __syncthreads();

    size_t base = (size_t)((c * 8 + h) * 5 + p) * 4096;
    int ar = 16 * w + (lane & 15);
    int kb = (lane >> 4) * 16;
    float dec_[4];
    #pragma unroll
    for (int j = 0; j < 4; ++j) dec_[j] = expf(glast[16 * w + (lane >> 4) * 4 + j]);

    #pragma unroll
    for (int ni = 0; ni < 4; ++ni) {
        f32x4 acc = (f32x4){0.f, 0.f, 0.f, 0.f};
        int br = 16 * ni + (lane & 15);
        #pragma unroll
        for (int kk = 0; kk < 6; ++kk) {
            s16x8 af = *(const s16x8*)((const char*)&kgT[ar][0] + kk * 64 + kb);
            s16x8 bf = *(const s16x8*)((const char*)&vT[br][0] + kk * 64 + kb);
            acc = __builtin_amdgcn_mfma_f32_16x16x32_bf16(af, bf, acc, 0, 0, 0);
        }
        #pragma unroll
        for (int j = 0; j < 4; ++j) {
            int dd = 16 * w + (lane >> 4) * 4 + j;
            kv_all[base + dd * 64 + 16 * ni + (lane & 15)] = acc[j] * dec_[j];
        }
    }
    if (tid < 64) decay_all[(size_t)((c * 8 + h) * 5 + p) * 64 + tid] = expf(glast[tid]);
}

// ---------------------------------------------------------------------------
// Inter-chunk state scan: elementwise, in place over kv_all (f32).
// ---------------------------------------------------------------------------
__global__ void gla_state_scan(float* __restrict__ kv, const float* __restrict__ decay)
{
    int gid = blockIdx.x * 256 + threadIdx.x;
    int sub = gid >> 6;
    const size_t stride = 8 * 5 * 64 * 64;
    float S = 0.f;
    float kvv = kv[gid];
    for (int c = 0; c < 64; ++c) {
        size_t o = (size_t)c * stride + gid;
        float nxt = (c < 63) ? kv[o + stride] : 0.f;
        float dec = decay[c * 2560 + sub];
        kv[o] = S;
        S = fmaf(dec, S, kvv);
        kvv = nxt;
    }
}

// ---------------------------------------------------------------------------
// Phase 2: per-pass output via bf16 MFMA. XCD swizzle over (p,h,c).
// ---------------------------------------------------------------------------
__global__ void gla_o(const float* __restrict__ q1, const float* __restrict__ q2,
                      const float* __restrict__ k1, const float* __restrict__ k2,
                      const float* __restrict__ gk1, const float* __restrict__ gk2,
                      const float* __restrict__ v, const float* __restrict__ rw,
                      const float* __restrict__ Spre,
                      float* __restrict__ o_dense, float* __restrict__ o_sparse)
{
    int flat = (blockIdx.z * 8 + blockIdx.y) * 5 + blockIdx.x;
    int sfl = (flat & 7) * 320 + (flat >> 3);
    int p = sfl % 5, h = (sfl / 5) & 7, c = sfl / 40;

    const float* qp = (p == 0) ? q1 : q2;
    const float* kp = (p == 0) ? k1 : k2;
    const float* gp = (p == 0) ? gk1 : gk2;

    __shared__ __align__(16) unsigned short qg_bf[64][72];  // [t][d]
    __shared__ __align__(16) unsigned short kg_bf[64][72];  // [s][d]
    __shared__ __align__(16) unsigned short A_bf[64][72];   // [t][s]
    __shared__ __align__(16) unsigned short vT_bf[64][72];  // [e][s]
    __shared__ __align__(16) unsigned short ST_bf[64][72];  // [e][d]
    __shared__ float wrow[64];
    __shared__ float segsum[4][64];

    int tid = threadIdx.x;
    int lane = tid & 63, w = tid >> 6;
    int d = lane, seg = w;

    {
        float gkv[16], qv[16], kvv[16];
        #pragma unroll
        for (int i = 0; i < 16; ++i) {
            size_t base = (size_t)(c * 64 + seg * 16 + i) * KD_ + (h << 6) + d;
            gkv[i] = gp[base];
            qv[i]  = qp[base];
            kvv[i] = kp[base];
        }
        if (tid < 64) {
            int lg = c * 64 + tid;
            wrow[tid] = (p == 0) ? 1.f : rw[lg * 4 + (p - 1)];
        }
        __syncthreads();

        float s = 0.f;
        #pragma unroll
        for (int i = 0; i < 16; ++i) {
            int t = seg * 16 + i;
            float xg = gkv[i];
            if (p > 0 && !(wrow[t] > 0.f)) xg = 0.f;
            s += xg;
            gkv[i] = s;
        }
        segsum[seg][d] = s;
        __syncthreads();

        float off = 0.f;
        for (int ss = 0; ss < seg; ++ss) off += segsum[ss][d];
        #pragma unroll
        for (int i = 0; i < 16; ++i) {
            int t = seg * 16 + i;
            float g = off + gkv[i];
            float wv = wrow[t];
            qg_bf[t][d] = f2bf(qv[i] * wv * expf(g));
            kg_bf[t][d] = f2bf(kvv[i] * wv * expf(-g));
        }
    }

    {
        size_t sbase = (size_t)((c * 8 + h) * 5 + p) * 4096;
        float Sv[16], vv_[16];
        #pragma unroll
        for (int i = 0; i < 16; ++i) Sv[i] = Spre[sbase + tid + (i << 8)];
        #pragma unroll
        for (int i = 0; i < 16; ++i)
            vv_[i] = v[(size_t)(c * 64 + seg * 16 + i) * KD_ + (h << 6) + d];
        #pragma unroll
        for (int i = 0; i < 16; ++i) ST_bf[d][4 * i + seg] = f2bf(Sv[i]);
        #pragma unroll
        for (int i = 0; i < 16; ++i) vT_bf[d][seg * 16 + i] = f2bf(vv_[i]);
    }
    __syncthreads();

    int am = 16 * w + (lane & 15);
    int kb = (lane >> 4) * 16;

    #pragma unroll
    for (int ni = 0; ni < 4; ++ni) {
        f32x4 acc = (f32x4){0.f, 0.f, 0.f, 0.f};
        if (ni <= w) {
            int br = 16 * ni + (lane & 15);
            #pragma unroll
            for (int kk = 0; kk < 2; ++kk) {
                s16x8 af = *(const s16x8*)((const char*)&qg_bf[am][0] + kk * 64 + kb);
                s16x8 bf = *(const s16x8*)((const char*)&kg_bf[br][0] + kk * 64 + kb);
                acc = __builtin_amdgcn_mfma_f32_16x16x32_bf16(af, bf, acc, 0, 0, 0);
            }
        }
        #pragma unroll
        for (int j = 0; j < 4; ++j) {
            int t = 16 * w + (lane >> 4) * 4 + j;
            int s = 16 * ni + (lane & 15);
            A_bf[t][s] = (s <= t) ? f2bf(acc[j]) : (unsigned short)0;
        }
    }
    __syncthreads();

    #pragma unroll
    for (int ni = 0; ni < 4; ++ni) {
        f32x4 acc = (f32x4){0.f, 0.f, 0.f, 0.f};
        int br = 16 * ni + (lane & 15);
        #pragma unroll
        for (int kk = 0; kk < 2; ++kk) {
            s16x8 af = *(const s16x8*)((const char*)&qg_bf[am][0] + kk * 64 + kb);
            s16x8 bf = *(const s16x8*)((const char*)&ST_bf[br][0] + kk * 64 + kb);
            acc = __builtin_amdgcn_mfma_f32_16x16x32_bf16(af, bf, acc, 0, 0, 0);
        }
        #pragma unroll
        for (int kk = 0; kk < 2; ++kk) {
            s16x8 af = *(const s16x8*)((const char*)&A_bf[am][0] + kk * 64 + kb);
            s16x8 bf = *(const s16x8*)((const char*)&vT_bf[br][0] + kk * 64 + kb);
            acc = __builtin_amdgcn_mfma_f32_16x16x32_bf16(af, bf, acc, 0, 0, 0);
        }
        #pragma unroll
        for (int j = 0; j < 4; ++j) {
            int t = 16 * w + (lane >> 4) * 4 + j;
            int e = 16 * ni + (lane & 15);
            size_t idx = (size_t)(c * 64 + t) * KD_ + (h << 6) + e;
            if (p == 0)                 o_dense[idx]  = acc[j];
            else if (wrow[t] > 0.f)     o_sparse[idx] = acc[j];
        }
    }
}

// ---------------------------------------------------------------------------
// Post: sum dense+sparse, RMS-norm, * norm_w, * silu(g); emit split-bf16 A.
// ---------------------------------------------------------------------------
__global__ void postnorm(const float* __restrict__ o_dense, const float* __restrict__ o_sparse,
                         const float* __restrict__ gbuf,
                         const float* __restrict__ norm_w, unsigned short* __restrict__ og2)
{
    int l = blockIdx.x;
    int tid = threadIdx.x;
    int w = tid >> 6, lane = tid & 63;
    int bi = (w << 6) + lane;
    int idx = l * KD_ + bi;
    float o = o_dense[idx] + o_sparse[idx];
    float ss = o * o;
    for (int s = 32; s >= 1; s >>= 1) ss += __shfl_xor(ss, s, 64);
    float r = rsqrtf(ss * (1.f / 64.f) + 1e-5f);
    float val = o * r * norm_w[lane];
    float gv = gbuf[idx];
    val *= gv / (1.f + expf(-gv));
    unsigned short h, lo;
    split2(val, h, lo);
    size_t ro = (size_t)l * (3 * KD_) + bi;
    og2[ro]           = h;
    og2[ro + KD_]     = lo;
    og2[ro + 2 * KD_] = h;
}

// ---------------------------------------------------------------------------
extern "C" void kernel_launch(void* const* d_in, const int* in_sizes, int n_in,
                              void* d_out, int out_size, void* d_ws, size_t ws_size,
                              hipStream_t stream)
{
    const float* x    = (const float*)d_in[0];
    const float* Wq   = (const float*)d_in[1];
    const float* Wk   = (const float*)d_in[2];
    const float* Wv   = (const float*)d_in[3];
    const float* Wqa  = (const float*)d_in[4];
    const float* Wqb  = (const float*)d_in[5];
    const float* Wka  = (const float*)d_in[6];
    const float* Wkb  = (const float*)d_in[7];
    const float* Wg1a = (const float*)d_in[8];
    const float* Wg1b = (const float*)d_in[9];
    const float* bg1  = (const float*)d_in[10];
    const float* Wg2a = (const float*)d_in[11];
    const float* Wg2b = (const float*)d_in[12];
    const float* bg2  = (const float*)d_in[13];
    const float* We   = (const float*)d_in[14];
    const float* Wga  = (const float*)d_in[15];
    const float* Wgb  = (const float*)d_in[16];
    const float* normw= (const float*)d_in[17];
    const float* Wo   = (const float*)d_in[18];

    float* ws = (float*)d_ws;
    const size_t LKD = (size_t)LL * KD_;   // 2M floats
    float* q1   = ws;
    float* k1   = q1 + LKD;
    float* v    = k1 + LKD;
    float* q2   = v  + LKD;
    float* k2   = q2 + LKD;
    float* gk1  = k2 + LKD;
    float* gk2  = gk1 + LKD;
    float* o_dense  = gk2 + LKD;
    float* o_sparse = o_dense + LKD;
    float* gbuf = o_sparse + LKD;
    float* elog = gbuf + LKD;                  // 4096*4
    float* rw   = elog + (size_t)LL * 4;
    float* kv_all    = rw + (size_t)LL * 4;                    // 10.49M f32
    float* decay_all = kv_all + (size_t)64 * 8 * 5 * 64 * 64;  // 163840 f32

    unsigned short* bp = (unsigned short*)(decay_all + 163840);
    unsigned short* WallT2 = bp; bp += (size_t)1792 * 3072;    // [Wq|Wk|Wv|Wcat]
    unsigned short* WoT2   = bp; bp += (size_t)1024 * 1536;
    unsigned short* WqbT2  = bp; bp += (size_t)512 * 192;
    unsigned short* WkbT2  = bp; bp += (size_t)512 * 192;
    unsigned short* WgbT2  = bp; bp += (size_t)512 * 192;
    unsigned short* Wg1bT2 = bp; bp += (size_t)512 * 64;
    unsigned short* Wg2bT2 = bp; bp += (size_t)512 * 64;
    unsigned short* tqab2  = bp; bp += (size_t)LL * 192;
    unsigned short* tkab2  = bp; bp += (size_t)LL * 192;
    unsigned short* tgab2  = bp; bp += (size_t)LL * 192;
    unsigned short* tg1s2  = bp; bp += (size_t)LL * 64;
    unsigned short* tg2s2  = bp; bp += (size_t)LL * 64;
    float* tcat = (float*)bp;                                  // 4096*256 f32

    // time-multiplexed aliases of kv_all (disjoint lifetimes):
    unsigned short* xb2 = (unsigned short*)kv_all;   // [4096][3072]; dead before gla_kv
    unsigned short* og2 = (unsigned short*)kv_all;   // [4096][1536]; live after gla_o

    dim3 blk(256);
    dim3 tblk(32, 8);

    // ---- conversions ----
    cvt_splitA<<<dim3((LL * 1024 + 255) / 256), blk, 0, stream>>>(x, xb2, LL * 1024, 10);
    hipMemsetAsync(WallT2 + (size_t)1764 * 3072, 0, (size_t)(1792 - 1764) * 3072 * 2, stream);
    cvt_weights_all<<<dim3(32, 32, 15), tblk, 0, stream>>>(
        Wq, Wk, Wv, Wqa, Wka, Wga, Wg1a, Wg2a, We, Wo, Wqb, Wkb, Wgb, Wg1b, Wg2b,
        WallT2, WoT2, WqbT2, WkbT2, WgbT2, Wg1bT2, Wg2bT2);

    // ---- mega GEMM: QKV + LoRA-a + gate-a + router (128x128 + prefetch dbuf) ----
    gemm_qkvcat<<<dim3(14, 32), blk, 0, stream>>>(xb2, WallT2, q1, k1, v, tcat, LL, 3072);
    unpack_cat<<<dim3(LL), blk, 0, stream>>>(tcat, tqab2, tkab2, tgab2, tg1s2, tg2s2, elog);

    // ---- LoRA-b q2,k2,gbuf + gate-b gk1,gk2 ----
    gemm_mfma5<<<dim3(4, 32, 5), blk, 0, stream>>>(
        tqab2, tkab2, tgab2, tg1s2, tg2s2,
        WqbT2, WkbT2, WgbT2, Wg1bT2, Wg2bT2,
        q2, k2, gbuf, gk1, gk2, LL, KD_);

    elementwise_pre<<<LL, 512, 0, stream>>>(q2, k2, gk1, gk2, bg1, bg2, elog, rw);

    // ---- GLA: kv -> scan -> o ----
    gla_kv<<<dim3(5, 8, 64), blk, 0, stream>>>(k1, k2, gk1, gk2, v, rw, kv_all, decay_all);
    gla_state_scan<<<dim3(640), blk, 0, stream>>>(kv_all, decay_all);
    gla_o<<<dim3(5, 8, 64), blk, 0, stream>>>(q1, q2, k1, k2, gk1, gk2, v, rw,
                                              kv_all, o_dense, o_sparse);

    postnorm<<<LL, 512, 0, stream>>>(o_dense, o_sparse, gbuf, normw, og2);

    // ---- output projection (64x128 tile, 512 blocks) ----
    gemm_mfma<<<dim3(8, 64), blk, 0, stream>>>(og2, WoT2, (float*)d_out, LL, 1024, 1536);
}

// Round 23
// 210.088 us; speedup vs baseline: 1.1069x; 1.0307x over previous
//
#include <hip/hip_runtime.h>
#include <math.h>

#define LL   4096
#define HH   8
#define DK_  64
#define DV_  64
#define KD_  512
#define NEXP 4

typedef __attribute__((ext_vector_type(8))) short  s16x8;
typedef __attribute__((ext_vector_type(4))) float  f32x4;

__device__ __forceinline__ unsigned short f2bf(float f) {   // RNE f32->bf16
    unsigned u = __float_as_uint(f);
    u += 0x7FFFu + ((u >> 16) & 1u);
    return (unsigned short)(u >> 16);
}

__device__ __forceinline__ void split2(float v, unsigned short& h, unsigned short& l) {
    h = f2bf(v);
    float hf = __uint_as_float((unsigned)h << 16);
    l = f2bf(v - hf);
}

__device__ __forceinline__ float logsig(float x) {
    return fminf(x, 0.f) - log1pf(expf(-fabsf(x)));
}

// ---------------------------------------------------------------------------
// f32 [M][K] -> split-bf16 A layout [M][3K] = [hi | lo | hi]. K = 2^kshift.
// ---------------------------------------------------------------------------
__global__ void cvt_splitA(const float* __restrict__ in, unsigned short* __restrict__ out,
                           int n, int kshift)
{
    int i = blockIdx.x * 256 + threadIdx.x;
    if (i >= n) return;
    unsigned short h, l;
    split2(in[i], h, l);
    int K = 1 << kshift;
    int m = i >> kshift, k = i & (K - 1);
    size_t ro = (size_t)m * 3 * K;
    out[ro + k]         = h;
    out[ro + K + k]     = l;
    out[ro + 2 * K + k] = h;
}

// ---------------------------------------------------------------------------
// ALL weight conversions in one launch. z selects the weight.
// f32 [K][N] -> split-bf16 B layout [N][ld] = [hi|hi|lo] (+zero pad for K=16).
// ---------------------------------------------------------------------------
__global__ void cvt_weights_all(
    const float* __restrict__ Wq,  const float* __restrict__ Wk,  const float* __restrict__ Wv,
    const float* __restrict__ Wqa, const float* __restrict__ Wka, const float* __restrict__ Wga,
    const float* __restrict__ Wg1a,const float* __restrict__ Wg2a,const float* __restrict__ We,
    const float* __restrict__ Wo,  const float* __restrict__ Wqb, const float* __restrict__ Wkb,
    const float* __restrict__ Wgb, const float* __restrict__ Wg1b,const float* __restrict__ Wg2b,
    unsigned short* __restrict__ WallT2, unsigned short* __restrict__ WoT2,
    unsigned short* __restrict__ WqbT2,  unsigned short* __restrict__ WkbT2,
    unsigned short* __restrict__ WgbT2,  unsigned short* __restrict__ Wg1bT2,
    unsigned short* __restrict__ Wg2bT2)
{
    int z = blockIdx.z;
    const float* W; unsigned short* WT; int K, N, ldr, pad = 0;
    switch (z) {
        case 0:  W = Wq;   WT = WallT2;                       K = 1024; N = 512;  ldr = 3072; break;
        case 1:  W = Wk;   WT = WallT2 + (size_t)512 * 3072;  K = 1024; N = 512;  ldr = 3072; break;
        case 2:  W = Wv;   WT = WallT2 + (size_t)1024 * 3072; K = 1024; N = 512;  ldr = 3072; break;
        case 3:  W = Wqa;  WT = WallT2 + (size_t)1536 * 3072; K = 1024; N = 64;   ldr = 3072; break;
        case 4:  W = Wka;  WT = WallT2 + (size_t)1600 * 3072; K = 1024; N = 64;   ldr = 3072; break;
        case 5:  W = Wga;  WT = WallT2 + (size_t)1664 * 3072; K = 1024; N = 64;   ldr = 3072; break;
        case 6:  W = Wg1a; WT = WallT2 + (size_t)1728 * 3072; K = 1024; N = 16;   ldr = 3072; break;
        case 7:  W = Wg2a; WT = WallT2 + (size_t)1744 * 3072; K = 1024; N = 16;   ldr = 3072; break;
        case 8:  W = We;   WT = WallT2 + (size_t)1760 * 3072; K = 1024; N = 4;    ldr = 3072; break;
        case 9:  W = Wo;   WT = WoT2;   K = 512; N = 1024; ldr = 1536; break;
        case 10: W = Wqb;  WT = WqbT2;  K = 64;  N = 512;  ldr = 192;  break;
        case 11: W = Wkb;  WT = WkbT2;  K = 64;  N = 512;  ldr = 192;  break;
        case 12: W = Wgb;  WT = WgbT2;  K = 64;  N = 512;  ldr = 192;  break;
        case 13: W = Wg1b; WT = Wg1bT2; K = 16;  N = 512;  ldr = 64; pad = 1; break;
        default: W = Wg2b; WT = Wg2bT2; K = 16;  N = 512;  ldr = 64; pad = 1; break;
    }
    int bx = blockIdx.x * 32, by = blockIdx.y * 32;
    if (bx >= N || by >= K) return;

    __shared__ float t[32][33];
    int x = threadIdx.x, y = threadIdx.y;
    #pragma unroll
    for (int i = 0; i < 4; ++i) {
        int kk = by + y + 8 * i;
        t[y + 8 * i][x] = (bx + x < N && kk < K) ? W[(size_t)kk * N + bx + x] : 0.f;
    }
    __syncthreads();
    #pragma unroll
    for (int i = 0; i < 4; ++i) {
        int n = bx + y + 8 * i;
        int kidx = by + x;
        if (n < N && kidx < K) {
            unsigned short h, l;
            split2(t[x][y + 8 * i], h, l);
            size_t ro = (size_t)n * ldr + kidx;
            WT[ro]         = h;
            WT[ro + K]     = h;
            WT[ro + 2 * K] = l;
        }
        if (pad && n < N && x < 16)
            WT[(size_t)n * ldr + 3 * K + x] = 0;
    }
}

// ---------------------------------------------------------------------------
// Mega GEMM: [q1|k1|v|tcat] = x @ [Wq|Wk|Wv|Wcat]. 128x128 tile, XCD swizzle,
// issue-early prefetch dbuf (measured +14us win at 1.75 blk/CU, r22).
// q1 scaled by 0.125 in epilogue.
// ---------------------------------------------------------------------------
__global__ __launch_bounds__(256) void gemm_qkvcat(
    const unsigned short* __restrict__ A, const unsigned short* __restrict__ B,
    float* __restrict__ Cq, float* __restrict__ Ck, float* __restrict__ Cv,
    float* __restrict__ Ct, int M, int K)
{
    __shared__ __align__(16) unsigned short sm[4 * 128 * 64];   // 2 bufs x (A+B)

    int bxi = blockIdx.x, byi = blockIdx.y;
    {
        int gx = gridDim.x, nwg = gx * gridDim.y;
        int b = byi * gx + bxi;
        int s = (b & 7) * (nwg >> 3) + (b >> 3);
        bxi = s % gx; byi = s / gx;
    }

    int tid  = threadIdx.x;
    int lane = tid & 63;
    int w    = tid >> 6;
    int m0 = byi * 128, n0 = bxi * 128;
    int wr = w >> 1, wc = w & 1;

    f32x4 acc[4][4];
    #pragma unroll
    for (int i = 0; i < 4; ++i)
        #pragma unroll
        for (int j = 0; j < 4; ++j)
            acc[i][j] = (f32x4){0.f, 0.f, 0.f, 0.f};

    const int srow = (lane >> 3);
    const int scb  = ((lane & 7) * 16) ^ (srow << 4);

    auto stage = [&](int buf, int kt) {
        unsigned short* Asb = sm + buf * (2 * 128 * 64);
        unsigned short* Bsb = Asb + 128 * 64;
        #pragma unroll
        for (int q = 0; q < 4; ++q) {
            int r = w * 32 + q * 8 + srow;
            const char* ga = (const char*)A + ((size_t)(m0 + r) * K + kt) * 2 + scb;
            const char* gb = (const char*)B + ((size_t)(n0 + r) * K + kt) * 2 + scb;
            __builtin_amdgcn_global_load_lds(
                (const __attribute__((address_space(1))) void*)ga,
                (__attribute__((address_space(3))) void*)((char*)Asb + (w * 32 + q * 8) * 128),
                16, 0, 0);
            __builtin_amdgcn_global_load_lds(
                (const __attribute__((address_space(1))) void*)gb,
                (__attribute__((address_space(3))) void*)((char*)Bsb + (w * 32 + q * 8) * 128),
                16, 0, 0);
        }
    };

    stage(0, 0);
    __syncthreads();
    int cur = 0;
    for (int kt = 0; kt < K; kt += 64) {
        if (kt + 64 < K) stage(cur ^ 1, kt + 64);
        unsigned short* Asb = sm + cur * (2 * 128 * 64);
        unsigned short* Bsb = Asb + 128 * 64;
        #pragma unroll
        for (int kk = 0; kk < 2; ++kk) {
            int kb = kk * 64 + (lane >> 4) * 16;
            s16x8 af[4], bfr[4];
            #pragma unroll
            for (int mi = 0; mi < 4; ++mi) {
                int r = wr * 64 + mi * 16 + (lane & 15);
                af[mi] = *(const s16x8*)((const char*)Asb + r * 128 + (kb ^ ((r & 7) << 4)));
            }
            #pragma unroll
            for (int ni = 0; ni < 4; ++ni) {
                int r = wc * 64 + ni * 16 + (lane & 15);
                bfr[ni] = *(const s16x8*)((const char*)Bsb + r * 128 + (kb ^ ((r & 7) << 4)));
            }
            #pragma unroll
            for (int mi = 0; mi < 4; ++mi)
                #pragma unroll
                for (int ni = 0; ni < 4; ++ni)
                    acc[mi][ni] = __builtin_amdgcn_mfma_f32_16x16x32_bf16(
                        af[mi], bfr[ni], acc[mi][ni], 0, 0, 0);
        }
        __syncthreads();
        cur ^= 1;
    }

    int base = n0 >> 9;
    float* C;
    int ldc, cb;
    float scale = 1.f;
    if (base == 0)      { C = Cq; ldc = 512; cb = 0; scale = 0.125f; }
    else if (base == 1) { C = Ck; ldc = 512; cb = 512; }
    else if (base == 2) { C = Cv; ldc = 512; cb = 1024; }
    else                { C = Ct; ldc = 256; cb = 1536; }

    #pragma unroll
    for (int mi = 0; mi < 4; ++mi)
        #pragma unroll
        for (int ni = 0; ni < 4; ++ni) {
            int col = n0 + wc * 64 + ni * 16 + (lane & 15) - cb;
            int rb  = m0 + wr * 64 + mi * 16 + (lane >> 4) * 4;
            #pragma unroll
            for (int j = 0; j < 4; ++j)
                C[(size_t)(rb + j) * ldc + col] = acc[mi][ni][j] * scale;
        }
}

// ---------------------------------------------------------------------------
// Split-bf16 MFMA GEMM (Wo). 64x128 tile, XCD swizzle, issue-early prefetch
// dbuf (48KB LDS, 512 blocks = 2/CU grid-limited regime).
// ---------------------------------------------------------------------------
__global__ __launch_bounds__(256) void gemm_mfma(
    const unsigned short* __restrict__ A, const unsigned short* __restrict__ B,
    float* __restrict__ C, int M, int N, int K)
{
    __shared__ __align__(16) unsigned short sm[2 * (64 * 64 + 128 * 64)];

    int bxi = blockIdx.x, byi = blockIdx.y;
    {
        int gx = gridDim.x, nwg = gx * gridDim.y;
        if ((nwg & 7) == 0) {
            int b = byi * gx + bxi;
            int s = (b & 7) * (nwg >> 3) + (b >> 3);
            bxi = s % gx; byi = s / gx;
        }
    }

    int tid  = threadIdx.x;
    int lane = tid & 63;
    int w    = tid >> 6;
    int m0 = byi * 64, n0 = bxi * 128;
    int wc = w & 1, wr = w >> 1;

    f32x4 acc[2][4];
    #pragma unroll
    for (int i = 0; i < 2; ++i)
        #pragma unroll
        for (int j = 0; j < 4; ++j)
            acc[i][j] = (f32x4){0.f, 0.f, 0.f, 0.f};

    const int srow = (lane >> 3);
    const int scb  = ((lane & 7) * 16) ^ (srow << 4);

    auto stage = [&](int buf, int kt) {
        unsigned short* Asb = sm + buf * (64 * 64 + 128 * 64);
        unsigned short* Bsb = Asb + 64 * 64;
        #pragma unroll
        for (int q = 0; q < 2; ++q) {
            int r = w * 16 + q * 8 + srow;
            const char* ga = (const char*)A + ((size_t)(m0 + r) * K + kt) * 2 + scb;
            __builtin_amdgcn_global_load_lds(
                (const __attribute__((address_space(1))) void*)ga,
                (__attribute__((address_space(3))) void*)((char*)Asb + (w * 16 + q * 8) * 128),
                16, 0, 0);
        }
        #pragma unroll
        for (int q = 0; q < 4; ++q) {
            int r = w * 32 + q * 8 + srow;
            const char* gb = (const char*)B + ((size_t)(n0 + r) * K + kt) * 2 + scb;
            __builtin_amdgcn_global_load_lds(
                (const __attribute__((address_space(1))) void*)gb,
                (__attribute__((address_space(3))) void*)((char*)Bsb + (w * 32 + q * 8) * 128),
                16, 0, 0);
        }
    };

    stage(0, 0);
    __syncthreads();
    int cur = 0;
    for (int kt = 0; kt < K; kt += 64) {
        if (kt + 64 < K) stage(cur ^ 1, kt + 64);
        unsigned short* Asb = sm + cur * (64 * 64 + 128 * 64);
        unsigned short* Bsb = Asb + 64 * 64;
        #pragma unroll
        for (int kk = 0; kk < 2; ++kk) {
            int kb = kk * 64 + (lane >> 4) * 16;
            s16x8 af[2], bfr[4];
            #pragma unroll
            for (int mi = 0; mi < 2; ++mi) {
                int r = wr * 32 + mi * 16 + (lane & 15);
                af[mi] = *(const s16x8*)((const char*)Asb + r * 128 + (kb ^ ((r & 7) << 4)));
            }
            #pragma unroll
            for (int ni = 0; ni < 4; ++ni) {
                int r = wc * 64 + ni * 16 + (lane & 15);
                bfr[ni] = *(const s16x8*)((const char*)Bsb + r * 128 + (kb ^ ((r & 7) << 4)));
            }
            #pragma unroll
            for (int mi = 0; mi < 2; ++mi)
                #pragma unroll
                for (int ni = 0; ni < 4; ++ni)
                    acc[mi][ni] = __builtin_amdgcn_mfma_f32_16x16x32_bf16(
                        af[mi], bfr[ni], acc[mi][ni], 0, 0, 0);
        }
        __syncthreads();
        cur ^= 1;
    }

    #pragma unroll
    for (int mi = 0; mi < 2; ++mi)
        #pragma unroll
        for (int ni = 0; ni < 4; ++ni) {
            int col = n0 + wc * 64 + ni * 16 + (lane & 15);
            int rb  = m0 + wr * 32 + mi * 16 + (lane >> 4) * 4;
            #pragma unroll
            for (int j = 0; j < 4; ++j)
                C[(size_t)(rb + j) * N + col] = acc[mi][ni][j];
        }
}

// ---------------------------------------------------------------------------
// Split-bf16 MFMA GEMM, 5-way z with per-z K (192,192,192,64,64). N=512.
// 128x128 tile, issue-early prefetch dbuf (K=192 pipelines 3 tiles; K=64
// degenerates to prologue only). Plain epilogue.
// ---------------------------------------------------------------------------
__global__ __launch_bounds__(256) void gemm_mfma5(
    const unsigned short* __restrict__ A0, const unsigned short* __restrict__ A1,
    const unsigned short* __restrict__ A2, const unsigned short* __restrict__ A3,
    const unsigned short* __restrict__ A4,
    const unsigned short* __restrict__ B0, const unsigned short* __restrict__ B1,
    const unsigned short* __restrict__ B2, const unsigned short* __restrict__ B3,
    const unsigned short* __restrict__ B4,
    float* __restrict__ C0, float* __restrict__ C1, float* __restrict__ C2,
    float* __restrict__ C3, float* __restrict__ C4, int M, int N)
{
    int z = blockIdx.z;
    const unsigned short* A = (z == 0) ? A0 : (z == 1) ? A1 : (z == 2) ? A2 : (z == 3) ? A3 : A4;
    const unsigned short* B = (z == 0) ? B0 : (z == 1) ? B1 : (z == 2) ? B2 : (z == 3) ? B3 : B4;
    float*                C = (z == 0) ? C0 : (z == 1) ? C1 : (z == 2) ? C2 : (z == 3) ? C3 : C4;
    int K = (z < 3) ? 192 : 64;

    __shared__ __align__(16) unsigned short sm[4 * 128 * 64];

    int bxi = blockIdx.x, byi = blockIdx.y;
    {
        int gx = gridDim.x, nwg = gx * gridDim.y;
        if ((nwg & 7) == 0) {
            int b = byi * gx + bxi;
            int s = (b & 7) * (nwg >> 3) + (b >> 3);
            bxi = s % gx; byi = s / gx;
        }
    }

    int tid  = threadIdx.x;
    int lane = tid & 63;
    int w    = tid >> 6;
    int m0 = byi * 128, n0 = bxi * 128;
    int wr = w >> 1, wc = w & 1;

    f32x4 acc[4][4];
    #pragma unroll
    for (int i = 0; i < 4; ++i)
        #pragma unroll
        for (int j = 0; j < 4; ++j)
            acc[i][j] = (f32x4){0.f, 0.f, 0.f, 0.f};

    const int srow = (lane >> 3);
    const int scb  = ((lane & 7) * 16) ^ (srow << 4);

    auto stage = [&](int buf, int kt) {
        unsigned short* Asb = sm + buf * (2 * 128 * 64);
        unsigned short* Bsb = Asb + 128 * 64;
        #pragma unroll
        for (int q = 0; q < 4; ++q) {
            int r = w * 32 + q * 8 + srow;
            const char* ga = (const char*)A + ((size_t)(m0 + r) * K + kt) * 2 + scb;
            const char* gb = (const char*)B + ((size_t)(n0 + r) * K + kt) * 2 + scb;
            __builtin_amdgcn_global_load_lds(
                (const __attribute__((address_space(1))) void*)ga,
                (__attribute__((address_space(3))) void*)((char*)Asb + (w * 32 + q * 8) * 128),
                16, 0, 0);
            __builtin_amdgcn_global_load_lds(
                (const __attribute__((address_space(1))) void*)gb,
                (__attribute__((address_space(3))) void*)((char*)Bsb + (w * 32 + q * 8) * 128),
                16, 0, 0);
        }
    };

    stage(0, 0);
    __syncthreads();
    int cur = 0;
    for (int kt = 0; kt < K; kt += 64) {
        if (kt + 64 < K) stage(cur ^ 1, kt + 64);
        unsigned short* Asb = sm + cur * (2 * 128 * 64);
        unsigned short* Bsb = Asb + 128 * 64;
        #pragma unroll
        for (int kk = 0; kk < 2; ++kk) {
            int kb = kk * 64 + (lane >> 4) * 16;
            s16x8 af[4], bfr[4];
            #pragma unroll
            for (int mi = 0; mi < 4; ++mi) {
                int r = wr * 64 + mi * 16 + (lane & 15);
                af[mi] = *(const s16x8*)((const char*)Asb + r * 128 + (kb ^ ((r & 7) << 4)));
            }
            #pragma unroll
            for (int ni = 0; ni < 4; ++ni) {
                int r = wc * 64 + ni * 16 + (lane & 15);
                bfr[ni] = *(const s16x8*)((const char*)Bsb + r * 128 + (kb ^ ((r & 7) << 4)));
            }
            #pragma unroll
            for (int mi = 0; mi < 4; ++mi)
                #pragma unroll
                for (int ni = 0; ni < 4; ++ni)
                    acc[mi][ni] = __builtin_amdgcn_mfma_f32_16x16x32_bf16(
                        af[mi], bfr[ni], acc[mi][ni], 0, 0, 0);
        }
        __syncthreads();
        cur ^= 1;
    }

    #pragma unroll
    for (int mi = 0; mi < 4; ++mi)
        #pragma unroll
        for (int ni = 0; ni < 4; ++ni) {
            int col = n0 + wc * 64 + ni * 16 + (lane & 15);
            int rb  = m0 + wr * 64 + mi * 16 + (lane >> 4) * 4;
            #pragma unroll
            for (int j = 0; j < 4; ++j)
                C[(size_t)(rb + j) * N + col] = acc[mi][ni][j];
        }
}

// ---------------------------------------------------------------------------
// Unpack tcat [LL][256]: LoRA-a -> split-bf16 [LL][192]; gate-a -> split-bf16
// [LL][64] (48 used + 16 zero pad); router -> elog f32.
// ---------------------------------------------------------------------------
__global__ void unpack_cat(const float* __restrict__ tcat,
                           unsigned short* __restrict__ tqab2,
                           unsigned short* __restrict__ tkab2,
                           unsigned short* __restrict__ tgab2,
                           unsigned short* __restrict__ tg1s2,
                           unsigned short* __restrict__ tg2s2,
                           float* __restrict__ elog)
{
    int m = blockIdx.x;
    int c = threadIdx.x;
    float vx = tcat[(size_t)m * 256 + c];
    if (c < 192) {
        unsigned short h, l;
        split2(vx, h, l);
        unsigned short* dst = (c < 64) ? tqab2 : (c < 128) ? tkab2 : tgab2;
        int cc = c & 63;
        size_t ro = (size_t)m * 192;
        dst[ro + cc]       = h;
        dst[ro + 64 + cc]  = l;
        dst[ro + 128 + cc] = h;
    } else if (c < 224) {
        unsigned short h, l;
        split2(vx, h, l);
        unsigned short* dst = (c < 208) ? tg1s2 : tg2s2;
        int cc = (c - 192) & 15;
        size_t ro = (size_t)m * 64;
        dst[ro + cc]      = h;
        dst[ro + 16 + cc] = l;
        dst[ro + 32 + cc] = h;
        dst[ro + 48 + cc] = 0;
    } else if (c < 228) {
        elog[(size_t)m * 4 + (c - 224)] = vx;
    }
}

// ---------------------------------------------------------------------------
// Elementwise: q2 scale, k2 softmax per head, gk logsig(+bias)/16, router.
// ---------------------------------------------------------------------------
__global__ void elementwise_pre(float* __restrict__ q2,
                                float* __restrict__ k2, float* __restrict__ gk1,
                                float* __restrict__ gk2,
                                const float* __restrict__ bg1, const float* __restrict__ bg2,
                                const float* __restrict__ elog, float* __restrict__ rw)
{
    int l = blockIdx.x;
    int tid = threadIdx.x;
    int w = tid >> 6, lane = tid & 63;
    int idx = l * KD_ + (w << 6) + lane;

    q2[idx] *= 0.125f;

    float kv = k2[idx];
    float m = kv;
    for (int s = 32; s >= 1; s >>= 1) m = fmaxf(m, __shfl_xor(m, s, 64));
    float ev = expf(kv - m);
    float ssum = ev;
    for (int s = 32; s >= 1; s >>= 1) ssum += __shfl_xor(ssum, s, 64);
    k2[idx] = ev / ssum;

    int bi = (w << 6) + lane;
    gk1[idx] = logsig(gk1[idx] + bg1[bi]) * (1.f / 16.f);
    gk2[idx] = logsig(gk2[idx] + bg2[bi]) * (1.f / 16.f);

    if (tid == 0) {
        float xs[4];
        float mm = -1e30f;
        for (int j = 0; j < 4; ++j) { xs[j] = elog[l * 4 + j]; mm = fmaxf(mm, xs[j]); }
        float s4 = 0.f;
        for (int j = 0; j < 4; ++j) { xs[j] = expf(xs[j] - mm); s4 += xs[j]; }
        for (int j = 0; j < 4; ++j) xs[j] /= s4;
        int arg = 0; float best = xs[0];
        for (int j = 1; j < 4; ++j) if (xs[j] > best) { best = xs[j]; arg = j; }
        for (int j = 0; j < 4; ++j) rw[l * 4 + j] = (j == arg) ? xs[j] : 0.f;
    }
}

// ---------------------------------------------------------------------------
// Phase 1: chunk_kv + decay via split-bf16 MFMA. XCD swizzle over (p,h,c).
// ---------------------------------------------------------------------------
__global__ void gla_kv(const float* __restrict__ k1, const float* __restrict__ k2,
                       const float* __restrict__ gk1, const float* __restrict__ gk2,
                       const float* __restrict__ v, const float* __restrict__ rw,
                       float* __restrict__ kv_all, float* __restrict__ decay_all)
{
    int flat = (blockIdx.z * 8 + blockIdx.y) * 5 + blockIdx.x;
    int sfl = (flat & 7) * 320 + (flat >> 3);
    int p = sfl % 5, h = (sfl / 5) & 7, c = sfl / 40;

    const float* kp = (p == 0) ? k1 : k2;
    const float* gp = (p == 0) ? gk1 : gk2;

    __shared__ __align__(16) unsigned short kgT[64][200];
    __shared__ __align__(16) unsigned short vT[64][200];
    __shared__ float glast[64];
    __shared__ float wrow[64];
    __shared__ float segsum[4][64];

    int tid = threadIdx.x;
    int lane = tid & 63, w = tid >> 6;
    int d = lane, seg = w;

    float gkv[16], kvv[16], vv_[16];
    #pragma unroll
    for (int i = 0; i < 16; ++i) {
        size_t base = (size_t)(c * 64 + seg * 16 + i) * KD_ + (h << 6) + d;
        gkv[i] = gp[base];
        kvv[i] = kp[base];
        vv_[i] = v[base];
    }
    if (tid < 64) {
        int lg = c * 64 + tid;
        wrow[tid] = (p == 0) ? 1.f : rw[lg * 4 + (p - 1)];
    }
    __syncthreads();

    {
        float s = 0.f;
        #pragma unroll
        for (int i = 0; i < 16; ++i) {
            int t = seg * 16 + i;
            float xg = gkv[i];
            if (p > 0 && !(wrow[t] > 0.f)) xg = 0.f;
            s += xg;
            gkv[i] = s;
        }
        segsum[seg][d] = s;
    }
    __syncthreads();
    {
        float off = 0.f, tot = 0.f;
        #pragma unroll
        for (int ss = 0; ss < 4; ++ss) {
            float x = segsum[ss][d];
            tot += x;
            if (ss < seg) off += x;
        }
        if (seg == 0) glast[d] = tot;
        #pragma unroll
        for (int i = 0; i < 16; ++i) {
            int t = seg * 16 + i;
            float g = off + gkv[i];
            float kgval = kvv[i] * wrow[t] * expf(-g);
            unsigned short hh, ll;
            split2(kgval, hh, ll);
            kgT[d][t] = hh; kgT[d][64 + t] = ll; kgT[d][128 + t] = hh;
            split2(vv_[i], hh, ll);
            vT[d][t] = hh; vT[d][64 + t] = hh; vT[d][128 + t] = ll;
        }
    }
    __syncthreads();

    size_t base = (size_t)((c * 8 + h) * 5 + p) * 4096;
    int ar = 16 * w + (lane & 15);
    int kb = (lane >> 4) * 16;
    float dec_[4];
    #pragma unroll
    for (int j = 0; j < 4; ++j) dec_[j] = expf(glast[16 * w + (lane >> 4) * 4 + j]);

    #pragma unroll
    for (int ni = 0; ni < 4; ++ni) {
        f32x4 acc = (f32x4){0.f, 0.f, 0.f, 0.f};
        int br = 16 * ni + (lane & 15);
        #pragma unroll
        for (int kk = 0; kk < 6; ++kk) {
            s16x8 af = *(const s16x8*)((const char*)&kgT[ar][0] + kk * 64 + kb);
            s16x8 bf = *(const s16x8*)((const char*)&vT[br][0] + kk * 64 + kb);
            acc = __builtin_amdgcn_mfma_f32_16x16x32_bf16(af, bf, acc, 0, 0, 0);
        }
        #pragma unroll
        for (int j = 0; j < 4; ++j) {
            int dd = 16 * w + (lane >> 4) * 4 + j;
            kv_all[base + dd * 64 + 16 * ni + (lane & 15)] = acc[j] * dec_[j];
        }
    }
    if (tid < 64) decay_all[(size_t)((c * 8 + h) * 5 + p) * 64 + tid] = expf(glast[tid]);
}

// ---------------------------------------------------------------------------
// Inter-chunk state scan: elementwise, in place over kv_all (f32).
// ---------------------------------------------------------------------------
__global__ void gla_state_scan(float* __restrict__ kv, const float* __restrict__ decay)
{
    int gid = blockIdx.x * 256 + threadIdx.x;
    int sub = gid >> 6;
    const size_t stride = 8 * 5 * 64 * 64;
    float S = 0.f;
    float kvv = kv[gid];
    for (int c = 0; c < 64; ++c) {
        size_t o = (size_t)c * stride + gid;
        float nxt = (c < 63) ? kv[o + stride] : 0.f;
        float dec = decay[c * 2560 + sub];
        kv[o] = S;
        S = fmaf(dec, S, kvv);
        kvv = nxt;
    }
}

// ---------------------------------------------------------------------------
// Phase 2: per-pass output via bf16 MFMA. XCD swizzle over (p,h,c).
// ---------------------------------------------------------------------------
__global__ void gla_o(const float* __restrict__ q1, const float* __restrict__ q2,
                      const float* __restrict__ k1, const float* __restrict__ k2,
                      const float* __restrict__ gk1, const float* __restrict__ gk2,
                      const float* __restrict__ v, const float* __restrict__ rw,
                      const float* __restrict__ Spre,
                      float* __restrict__ o_dense, float* __restrict__ o_sparse)
{
    int flat = (blockIdx.z * 8 + blockIdx.y) * 5 + blockIdx.x;
    int sfl = (flat & 7) * 320 + (flat >> 3);
    int p = sfl % 5, h = (sfl / 5) & 7, c = sfl / 40;

    const float* qp = (p == 0) ? q1 : q2;
    const float* kp = (p == 0) ? k1 : k2;
    const float* gp = (p == 0) ? gk1 : gk2;

    __shared__ __align__(16) unsigned short qg_bf[64][72];
    __shared__ __align__(16) unsigned short kg_bf[64][72];
    __shared__ __align__(16) unsigned short A_bf[64][72];
    __shared__ __align__(16) unsigned short vT_bf[64][72];
    __shared__ __align__(16) unsigned short ST_bf[64][72];
    __shared__ float wrow[64];
    __shared__ float segsum[4][64];

    int tid = threadIdx.x;
    int lane = tid & 63, w = tid >> 6;
    int d = lane, seg = w;

    {
        float gkv[16], qv[16], kvv[16];
        #pragma unroll
        for (int i = 0; i < 16; ++i) {
            size_t base = (size_t)(c * 64 + seg * 16 + i) * KD_ + (h << 6) + d;
            gkv[i] = gp[base];
            qv[i]  = qp[base];
            kvv[i] = kp[base];
        }
        if (tid < 64) {
            int lg = c * 64 + tid;
            wrow[tid] = (p == 0) ? 1.f : rw[lg * 4 + (p - 1)];
        }
        __syncthreads();

        float s = 0.f;
        #pragma unroll
        for (int i = 0; i < 16; ++i) {
            int t = seg * 16 + i;
            float xg = gkv[i];
            if (p > 0 && !(wrow[t] > 0.f)) xg = 0.f;
            s += xg;
            gkv[i] = s;
        }
        segsum[seg][d] = s;
        __syncthreads();

        float off = 0.f;
        for (int ss = 0; ss < seg; ++ss) off += segsum[ss][d];
        #pragma unroll
        for (int i = 0; i < 16; ++i) {
            int t = seg * 16 + i;
            float g = off + gkv[i];
            float wv = wrow[t];
            qg_bf[t][d] = f2bf(qv[i] * wv * expf(g));
            kg_bf[t][d] = f2bf(kvv[i] * wv * expf(-g));
        }
    }

    {
        size_t sbase = (size_t)((c * 8 + h) * 5 + p) * 4096;
        float Sv[16], vv_[16];
        #pragma unroll
        for (int i = 0; i < 16; ++i) Sv[i] = Spre[sbase + tid + (i << 8)];
        #pragma unroll
        for (int i = 0; i < 16; ++i)
            vv_[i] = v[(size_t)(c * 64 + seg * 16 + i) * KD_ + (h << 6) + d];
        #pragma unroll
        for (int i = 0; i < 16; ++i) ST_bf[d][4 * i + seg] = f2bf(Sv[i]);
        #pragma unroll
        for (int i = 0; i < 16; ++i) vT_bf[d][seg * 16 + i] = f2bf(vv_[i]);
    }
    __syncthreads();

    int am = 16 * w + (lane & 15);
    int kb = (lane >> 4) * 16;

    #pragma unroll
    for (int ni = 0; ni < 4; ++ni) {
        f32x4 acc = (f32x4){0.f, 0.f, 0.f, 0.f};
        if (ni <= w) {
            int br = 16 * ni + (lane & 15);
            #pragma unroll
            for (int kk = 0; kk < 2; ++kk) {
                s16x8 af = *(const s16x8*)((const char*)&qg_bf[am][0] + kk * 64 + kb);
                s16x8 bf = *(const s16x8*)((const char*)&kg_bf[br][0] + kk * 64 + kb);
                acc = __builtin_amdgcn_mfma_f32_16x16x32_bf16(af, bf, acc, 0, 0, 0);
            }
        }
        #pragma unroll
        for (int j = 0; j < 4; ++j) {
            int t = 16 * w + (lane >> 4) * 4 + j;
            int s = 16 * ni + (lane & 15);
            A_bf[t][s] = (s <= t) ? f2bf(acc[j]) : (unsigned short)0;
        }
    }
    __syncthreads();

    #pragma unroll
    for (int ni = 0; ni < 4; ++ni) {
        f32x4 acc = (f32x4){0.f, 0.f, 0.f, 0.f};
        int br = 16 * ni + (lane & 15);
        #pragma unroll
        for (int kk = 0; kk < 2; ++kk) {
            s16x8 af = *(const s16x8*)((const char*)&qg_bf[am][0] + kk * 64 + kb);
            s16x8 bf = *(const s16x8*)((const char*)&ST_bf[br][0] + kk * 64 + kb);
            acc = __builtin_amdgcn_mfma_f32_16x16x32_bf16(af, bf, acc, 0, 0, 0);
        }
        #pragma unroll
        for (int kk = 0; kk < 2; ++kk) {
            s16x8 af = *(const s16x8*)((const char*)&A_bf[am][0] + kk * 64 + kb);
            s16x8 bf = *(const s16x8*)((const char*)&vT_bf[br][0] + kk * 64 + kb);
            acc = __builtin_amdgcn_mfma_f32_16x16x32_bf16(af, bf, acc, 0, 0, 0);
        }
        #pragma unroll
        for (int j = 0; j < 4; ++j) {
            int t = 16 * w + (lane >> 4) * 4 + j;
            int e = 16 * ni + (lane & 15);
            size_t idx = (size_t)(c * 64 + t) * KD_ + (h << 6) + e;
            if (p == 0)                 o_dense[idx]  = acc[j];
            else if (wrow[t] > 0.f)     o_sparse[idx] = acc[j];
        }
    }
}

// ---------------------------------------------------------------------------
// Post: sum dense+sparse, RMS-norm, * norm_w, * silu(g); emit split-bf16 A.
// ---------------------------------------------------------------------------
__global__ void postnorm(const float* __restrict__ o_dense, const float* __restrict__ o_sparse,
                         const float* __restrict__ gbuf,
                         const float* __restrict__ norm_w, unsigned short* __restrict__ og2)
{
    int l = blockIdx.x;
    int tid = threadIdx.x;
    int w = tid >> 6, lane = tid & 63;
    int bi = (w << 6) + lane;
    int idx = l * KD_ + bi;
    float o = o_dense[idx] + o_sparse[idx];
    float ss = o * o;
    for (int s = 32; s >= 1; s >>= 1) ss += __shfl_xor(ss, s, 64);
    float r = rsqrtf(ss * (1.f / 64.f) + 1e-5f);
    float val = o * r * norm_w[lane];
    float gv = gbuf[idx];
    val *= gv / (1.f + expf(-gv));
    unsigned short h, lo;
    split2(val, h, lo);
    size_t ro = (size_t)l * (3 * KD_) + bi;
    og2[ro]           = h;
    og2[ro + KD_]     = lo;
    og2[ro + 2 * KD_] = h;
}

// ---------------------------------------------------------------------------
extern "C" void kernel_launch(void* const* d_in, const int* in_sizes, int n_in,
                              void* d_out, int out_size, void* d_ws, size_t ws_size,
                              hipStream_t stream)
{
    const float* x    = (const float*)d_in[0];
    const float* Wq   = (const float*)d_in[1];
    const float* Wk   = (const float*)d_in[2];
    const float* Wv   = (const float*)d_in[3];
    const float* Wqa  = (const float*)d_in[4];
    const float* Wqb  = (const float*)d_in[5];
    const float* Wka  = (const float*)d_in[6];
    const float* Wkb  = (const float*)d_in[7];
    const float* Wg1a = (const float*)d_in[8];
    const float* Wg1b = (const float*)d_in[9];
    const float* bg1  = (const float*)d_in[10];
    const float* Wg2a = (const float*)d_in[11];
    const float* Wg2b = (const float*)d_in[12];
    const float* bg2  = (const float*)d_in[13];
    const float* We   = (const float*)d_in[14];
    const float* Wga  = (const float*)d_in[15];
    const float* Wgb  = (const float*)d_in[16];
    const float* normw= (const float*)d_in[17];
    const float* Wo   = (const float*)d_in[18];

    float* ws = (float*)d_ws;
    const size_t LKD = (size_t)LL * KD_;   // 2M floats
    float* q1   = ws;
    float* k1   = q1 + LKD;
    float* v    = k1 + LKD;
    float* q2   = v  + LKD;
    float* k2   = q2 + LKD;
    float* gk1  = k2 + LKD;
    float* gk2  = gk1 + LKD;
    float* o_dense  = gk2 + LKD;
    float* o_sparse = o_dense + LKD;
    float* gbuf = o_sparse + LKD;
    float* elog = gbuf + LKD;                  // 4096*4
    float* rw   = elog + (size_t)LL * 4;
    float* kv_all    = rw + (size_t)LL * 4;                    // 10.49M f32
    float* decay_all = kv_all + (size_t)64 * 8 * 5 * 64 * 64;  // 163840 f32

    unsigned short* bp = (unsigned short*)(decay_all + 163840);
    unsigned short* WallT2 = bp; bp += (size_t)1792 * 3072;    // [Wq|Wk|Wv|Wcat]
    unsigned short* WoT2   = bp; bp += (size_t)1024 * 1536;
    unsigned short* WqbT2  = bp; bp += (size_t)512 * 192;
    unsigned short* WkbT2  = bp; bp += (size_t)512 * 192;
    unsigned short* WgbT2  = bp; bp += (size_t)512 * 192;
    unsigned short* Wg1bT2 = bp; bp += (size_t)512 * 64;
    unsigned short* Wg2bT2 = bp; bp += (size_t)512 * 64;
    unsigned short* tqab2  = bp; bp += (size_t)LL * 192;
    unsigned short* tkab2  = bp; bp += (size_t)LL * 192;
    unsigned short* tgab2  = bp; bp += (size_t)LL * 192;
    unsigned short* tg1s2  = bp; bp += (size_t)LL * 64;
    unsigned short* tg2s2  = bp; bp += (size_t)LL * 64;
    float* tcat = (float*)bp;                                  // 4096*256 f32

    // time-multiplexed aliases of kv_all (disjoint lifetimes):
    unsigned short* xb2 = (unsigned short*)kv_all;   // [4096][3072]; dead before gla_kv
    unsigned short* og2 = (unsigned short*)kv_all;   // [4096][1536]; live after gla_o

    dim3 blk(256);
    dim3 tblk(32, 8);

    // ---- conversions ----
    cvt_splitA<<<dim3((LL * 1024 + 255) / 256), blk, 0, stream>>>(x, xb2, LL * 1024, 10);
    hipMemsetAsync(WallT2 + (size_t)1764 * 3072, 0, (size_t)(1792 - 1764) * 3072 * 2, stream);
    cvt_weights_all<<<dim3(32, 32, 15), tblk, 0, stream>>>(
        Wq, Wk, Wv, Wqa, Wka, Wga, Wg1a, Wg2a, We, Wo, Wqb, Wkb, Wgb, Wg1b, Wg2b,
        WallT2, WoT2, WqbT2, WkbT2, WgbT2, Wg1bT2, Wg2bT2);

    // ---- mega GEMM: QKV + LoRA-a + gate-a + router (128x128 + prefetch dbuf) ----
    gemm_qkvcat<<<dim3(14, 32), blk, 0, stream>>>(xb2, WallT2, q1, k1, v, tcat, LL, 3072);
    unpack_cat<<<dim3(LL), blk, 0, stream>>>(tcat, tqab2, tkab2, tgab2, tg1s2, tg2s2, elog);

    // ---- LoRA-b q2,k2,gbuf + gate-b gk1,gk2 (prefetch dbuf) ----
    gemm_mfma5<<<dim3(4, 32, 5), blk, 0, stream>>>(
        tqab2, tkab2, tgab2, tg1s2, tg2s2,
        WqbT2, WkbT2, WgbT2, Wg1bT2, Wg2bT2,
        q2, k2, gbuf, gk1, gk2, LL, KD_);

    elementwise_pre<<<LL, 512, 0, stream>>>(q2, k2, gk1, gk2, bg1, bg2, elog, rw);

    // ---- GLA: kv -> scan -> o ----
    gla_kv<<<dim3(5, 8, 64), blk, 0, stream>>>(k1, k2, gk1, gk2, v, rw, kv_all, decay_all);
    gla_state_scan<<<dim3(640), blk, 0, stream>>>(kv_all, decay_all);
    gla_o<<<dim3(5, 8, 64), blk, 0, stream>>>(q1, q2, k1, k2, gk1, gk2, v, rw,
                                              kv_all, o_dense, o_sparse);

    postnorm<<<LL, 512, 0, stream>>>(o_dense, o_sparse, gbuf, normw, og2);

    // ---- output projection (64x128 tile + prefetch dbuf, 512 blocks) ----
    gemm_mfma<<<dim3(8, 64), blk, 0, stream>>>(og2, WoT2, (float*)d_out, LL, 1024, 1536);
}